// Round 9
// baseline (12667.567 us; speedup 1.0000x reference)
//
#include <hip/hip_runtime.h>

// Output layout (flat f32, reference return order):
//   xhat  : B*L*N   = 13,107,200  @ 0
//   mu    : B*D     =      4,096  @ 13,107,200
//   logvar: B*D     =      4,096  @ 13,111,296
//   z_traj: B*L*D   =    819,200  @ 13,115,392
//   zdiff : B*(L-1)*D =  815,104  @ 13,934,592
#define OFF_MU   13107200
#define OFF_LV   13111296
#define OFF_ZT   13115392
#define OFF_ZD   13934592

typedef float v2f __attribute__((ext_vector_type(2)));

__device__ __forceinline__ float silu_f(float x) {
    return x / (1.0f + __expf(-x));
}

__device__ __forceinline__ float readlane_f(float v, int l) {
    return __uint_as_float(__builtin_amdgcn_readlane(__float_as_uint(v), l));
}

__device__ __forceinline__ v2f fma2(v2f a, v2f b, v2f c) {
    return __builtin_elementwise_fma(a, b, c);
}

// x + dpp_move(x) with compile-time DPP control. VALU-latency cross-lane.
template <int CTRL>
__device__ __forceinline__ float dppadd(float x) {
    int y = __builtin_amdgcn_update_dpp(0, __float_as_int(x), CTRL, 0xF, 0xF, true);
    return x + __int_as_float(y);
}

// Sum of x over each 16-lane row (values replicated per row afterwards).
__device__ __forceinline__ float sum16_dpp(float x) {
    x = dppadd<0xB1>(x);    // quad_perm xor1
    x = dppadd<0x4E>(x);    // quad_perm xor2
    x = dppadd<0x141>(x);   // row_half_mirror (xor4 once quad-uniform)
    x = dppadd<0x140>(x);   // row_mirror (xor8 once 8-uniform)
    return x;
}

// ---------------------------------------------------------------------------
// Encoder: one block per batch row. x0(256) -> 512 -> 256 -> 128 -> mu/lv(16)
// (unchanged — negligible cost)
// ---------------------------------------------------------------------------
__global__ __launch_bounds__(256) void enc_kernel(
    const float* __restrict__ xseq, const float* __restrict__ eps,
    const float* __restrict__ w1, const float* __restrict__ b1,
    const float* __restrict__ w2, const float* __restrict__ b2,
    const float* __restrict__ w3, const float* __restrict__ b3,
    const float* __restrict__ muw, const float* __restrict__ mub,
    const float* __restrict__ lvw, const float* __restrict__ lvb,
    float* __restrict__ out)
{
    __shared__ float xr[256];
    __shared__ float h1[512];
    __shared__ float h2[256];
    __shared__ float h3[128];

    const int t = threadIdx.x;
    const int b = blockIdx.x;

    xr[t] = xseq[b * (200 * 256) + t];
    __syncthreads();

    {
        float acc0 = b1[t], acc1 = b1[t + 256];
        for (int i = 0; i < 256; ++i) {
            float xv = xr[i];
            acc0 = fmaf(xv, w1[i * 512 + t],       acc0);
            acc1 = fmaf(xv, w1[i * 512 + t + 256], acc1);
        }
        h1[t]       = fmaxf(acc0, 0.0f);
        h1[t + 256] = fmaxf(acc1, 0.0f);
    }
    __syncthreads();

    {
        float acc = b2[t];
        for (int i = 0; i < 512; ++i) acc = fmaf(h1[i], w2[i * 256 + t], acc);
        h2[t] = fmaxf(acc, 0.0f);
    }
    __syncthreads();

    if (t < 128) {
        float acc = b3[t];
        for (int i = 0; i < 256; ++i) acc = fmaf(h2[i], w3[i * 128 + t], acc);
        h3[t] = fmaxf(acc, 0.0f);
    }
    __syncthreads();

    if (t < 16) {
        float mu = mub[t], lv = lvb[t];
        for (int i = 0; i < 128; ++i) {
            float hv = h3[i];
            mu = fmaf(hv, muw[i * 16 + t], mu);
            lv = fmaf(hv, lvw[i * 16 + t], lv);
        }
        out[OFF_MU + b * 16 + t] = mu;
        out[OFF_LV + b * 16 + t] = lv;
        float z0 = mu + __expf(0.5f * lv) * eps[b * 16 + t];
        out[OFF_ZT + b * 3200 + t] = z0;
    }
}

// ---------------------------------------------------------------------------
// ODE integrator v9: v8's 4-wave K-split-4 shape + TWO batch elements per
// block (manual 2-way SMT).
//   R8 post-mortem: v8 = 1807 cyc/feval, ~580 issue + ~1230 exposed serial
//   latency (LDS turnarounds, 2 barriers, DPP chains) — 1 wave/SIMD has
//   nothing to fill the gaps. Elements share WEIGHTS (zero extra weight
//   regs); only z/k state doubles. feval2 computes both elements in
//   straight-line code -> compiler interleaves the two independent chains;
//   A's latency hides under B's compute. Barriers shared: 2 per feval-PAIR.
//   Combine phase: threads 0-127 -> element A, 128-255 -> element B.
//   Grid = 128 blocks (elements 2b, 2b+1); wall time per feval-step is what
//   counts, idle CUs don't.
// ---------------------------------------------------------------------------
__global__ __launch_bounds__(256, 1) void ode_kernel(
    const float* __restrict__ tvec,
    const float* __restrict__ ow1, const float* __restrict__ ob1,
    const float* __restrict__ ow2, const float* __restrict__ ob2,
    const float* __restrict__ ow3, const float* __restrict__ ob3,
    const float* __restrict__ lng, const float* __restrict__ lnb,
    float* __restrict__ out)
{
    __shared__ __align__(16) float a1s[2][4][32];   // [elem][wave][col]
    __shared__ __align__(16) float part[2][4 * 128];
    __shared__ __align__(16) float a2s[2][128];
    __shared__ __align__(16) float p3s[2][4 * 64];

    const int tid  = threadIdx.x;
    const int wv   = tid >> 6;       // wave id 0..3 = K-quarter
    const int lane = tid & 63;
    const int b    = blockIdx.x;     // 0..127
    const int d    = lane & 15;      // owned z-dim (replicated x4 per wave)
    const int g    = lane >> 4;      // L3 K-chunk group
    const int c0   = lane, c1 = lane + 64;      // L2 output columns
    const int col1 = 32 * wv + (lane & 31);     // L1 column (lanes<32 write)

    // ---- register-resident weights via volatile (loaded exactly once) -----
    const volatile float* vw1 = ow1;
    const volatile float* vw2 = ow2;
    const volatile float* vw3 = ow3;

    float w1r[16];
#pragma unroll
    for (int k = 0; k < 16; ++k) w1r[k] = vw1[k * 128 + col1];

    v2f w2r0[16], w2r1[16];          // K-quarter wv, cols c0/c1, K-pairs
#pragma unroll
    for (int q = 0; q < 16; ++q) {
        int k0 = 32 * wv + 2 * q;
        v2f t0 = { vw2[k0 * 128 + c0], vw2[(k0 + 1) * 128 + c0] };
        v2f t1 = { vw2[k0 * 128 + c1], vw2[(k0 + 1) * 128 + c1] };
        w2r0[q] = t0;
        w2r1[q] = t1;
    }
    v2f w3r[16];   // K-chunk g (32 wide), stored in bank-staggered read order
#pragma unroll
    for (int qq = 0; qq < 8; ++qq) {
        int qsel = (qq + 2 * g) & 7;
        int k0   = 32 * g + 4 * qsel;
        v2f t0 = { vw3[(k0 + 0) * 16 + d], vw3[(k0 + 1) * 16 + d] };
        v2f t1 = { vw3[(k0 + 2) * 16 + d], vw3[(k0 + 3) * 16 + d] };
        w3r[2 * qq]     = t0;
        w3r[2 * qq + 1] = t1;
    }
    const volatile float* vb1 = ob1;
    const volatile float* vb2 = ob2;
    const volatile float* vb3 = ob3;
    const volatile float* vlg = lng;
    const volatile float* vlb = lnb;
    const float b1c  = vb1[col1];
    const float b2t  = vb2[tid & 127];   // combine bias (A: tid<128, B: tid>=128)
    const float b3d  = vb3[d];
    const float lngd = vlg[d], lnbd = vlb[d];

    float* ztrajA = out + OFF_ZT + (2 * b)     * 3200;
    float* ztrajB = out + OFF_ZT + (2 * b + 1) * 3200;
    float* zdiffA = out + OFF_ZD + (2 * b)     * 3184;
    float* zdiffB = out + OFF_ZD + (2 * b + 1) * 3184;

    float zA = ztrajA[d];            // z0, replicated, all waves
    float zB = ztrajB[d];

    // one paired evaluation: rA = f(zaA) for elem A, rB = f(zaB) for elem B.
    // Straight-line A/B code -> compiler interleaves the independent chains.
    auto feval2 = [&](float zaA, float zaB, float& rA, float& rB) {
        // L1: this wave's 32 a1 columns, both elements.
        float aeA = 0.0f, aoA = 0.0f, aeB = 0.0f, aoB = 0.0f;
#pragma unroll
        for (int k = 0; k < 16; k += 2) {
            float zA0 = readlane_f(zaA, k);
            float zA1 = readlane_f(zaA, k + 1);
            float zB0 = readlane_f(zaB, k);
            float zB1 = readlane_f(zaB, k + 1);
            aeA = fmaf(zA0, w1r[k],     aeA);
            aoA = fmaf(zA1, w1r[k + 1], aoA);
            aeB = fmaf(zB0, w1r[k],     aeB);
            aoB = fmaf(zB1, w1r[k + 1], aoB);
        }
        if (lane < 32) {
            a1s[0][wv][lane & 31] = silu_f(aeA + aoA + b1c);
            a1s[1][wv][lane & 31] = silu_f(aeB + aoB + b1c);
        }
        // intra-wave write->read: compiler inserts lgkmcnt, no barrier

        // L2 partials: K-range [32wv,32wv+32), 2 cols/lane, both elements.
        v2f AA = {0.f,0.f}, AAb = {0.f,0.f}, BA = {0.f,0.f}, BAb = {0.f,0.f};
        v2f AB = {0.f,0.f}, ABb = {0.f,0.f}, BB = {0.f,0.f}, BBb = {0.f,0.f};
        const float4* a4A = (const float4*)a1s[0][wv];
        const float4* a4B = (const float4*)a1s[1][wv];
#pragma unroll
        for (int i = 0; i < 8; ++i) {
            float4 avA = a4A[i];
            float4 avB = a4B[i];
            v2f pAl = { avA.x, avA.y }, pAh = { avA.z, avA.w };
            v2f pBl = { avB.x, avB.y }, pBh = { avB.z, avB.w };
            AA  = fma2(pAl, w2r0[2 * i],     AA);
            AAb = fma2(pAh, w2r0[2 * i + 1], AAb);
            BA  = fma2(pAl, w2r1[2 * i],     BA);
            BAb = fma2(pAh, w2r1[2 * i + 1], BAb);
            AB  = fma2(pBl, w2r0[2 * i],     AB);
            ABb = fma2(pBh, w2r0[2 * i + 1], ABb);
            BB  = fma2(pBl, w2r1[2 * i],     BB);
            BBb = fma2(pBh, w2r1[2 * i + 1], BBb);
        }
        part[0][wv * 128 + c0] = AA.x + AA.y + AAb.x + AAb.y;
        part[0][wv * 128 + c1] = BA.x + BA.y + BAb.x + BAb.y;
        part[1][wv * 128 + c0] = AB.x + AB.y + ABb.x + ABb.y;
        part[1][wv * 128 + c1] = BB.x + BB.y + BBb.x + BBb.y;
        __syncthreads();                     // barrier 1 (shared by A and B)

        // combine: threads 0..127 -> elem A, threads 128..255 -> elem B
        {
            const int e  = tid >> 7;         // 0 or 1
            const int t2 = tid & 127;
            float s = part[e][t2] + part[e][128 + t2]
                    + part[e][256 + t2] + part[e][384 + t2] + b2t;
            a2s[e][t2] = silu_f(s);
        }
        __syncthreads();                     // barrier 2

        // L3 (replicated in all waves), both elements.
        v2f ppA = {0.f, 0.f}, ppB = {0.f, 0.f};
#pragma unroll
        for (int qq = 0; qq < 8; ++qq) {
            int qsel = (qq + 2 * g) & 7;
            float4 avA = *(const float4*)&a2s[0][32 * g + 4 * qsel];
            float4 avB = *(const float4*)&a2s[1][32 * g + 4 * qsel];
            ppA = fma2((v2f){ avA.x, avA.y }, w3r[2 * qq],     ppA);
            ppA = fma2((v2f){ avA.z, avA.w }, w3r[2 * qq + 1], ppA);
            ppB = fma2((v2f){ avB.x, avB.y }, w3r[2 * qq],     ppB);
            ppB = fma2((v2f){ avB.z, avB.w }, w3r[2 * qq + 1], ppB);
        }
        // cross-group combine via wave-private LDS (one round trip each)
        p3s[0][wv * 64 + lane] = ppA.x + ppA.y;
        p3s[1][wv * 64 + lane] = ppB.x + ppB.y;
        const int pb = wv * 64 + d;
        float dzA = b3d + p3s[0][pb] + p3s[0][pb + 16]
                        + p3s[0][pb + 32] + p3s[0][pb + 48];
        float dzB = b3d + p3s[1][pb] + p3s[1][pb + 16]
                        + p3s[1][pb + 32] + p3s[1][pb + 48];

        // One-pass LayerNorm, both elements (4 independent DPP chains).
        float s1A = sum16_dpp(dzA);
        float s2A = sum16_dpp(dzA * dzA);
        float s1B = sum16_dpp(dzB);
        float s2B = sum16_dpp(dzB * dzB);
        float mA  = s1A * 0.0625f;
        float mB  = s1B * 0.0625f;
        float vA  = fmaf(mA, -mA, s2A * 0.0625f);
        float vB  = fmaf(mB, -mB, s2B * 0.0625f);
        rA = (dzA - mA) * rsqrtf(vA + 1e-5f) * lngd + lnbd;
        rB = (dzB - mB) * rsqrtf(vB + 1e-5f) * lngd + lnbd;
    };

    for (int l = 0; l < 199; ++l) {
        const float dt = tvec[l + 1] - tvec[l];
        const float h  = dt * 0.125f;          // dt / K, K=8 (exact)
        const float zsA = zA, zsB = zB;
        for (int s = 0; s < 8; ++s) {
            float k1A, k1B, k2A, k2B, k3A, k3B, k4A, k4B, k5A, k5B, k6A, k6B;
            feval2(zA, zB, k1A, k1B);
            feval2(zA + h * (k1A * (float)(1.0 / 5.0)),
                   zB + h * (k1B * (float)(1.0 / 5.0)), k2A, k2B);
            feval2(zA + h * ((float)(3.0 / 40.0) * k1A + (float)(9.0 / 40.0) * k2A),
                   zB + h * ((float)(3.0 / 40.0) * k1B + (float)(9.0 / 40.0) * k2B), k3A, k3B);
            feval2(zA + h * ((float)(44.0 / 45.0) * k1A - (float)(56.0 / 15.0) * k2A
                           + (float)(32.0 / 9.0) * k3A),
                   zB + h * ((float)(44.0 / 45.0) * k1B - (float)(56.0 / 15.0) * k2B
                           + (float)(32.0 / 9.0) * k3B), k4A, k4B);
            feval2(zA + h * ((float)(19372.0 / 6561.0) * k1A - (float)(25360.0 / 2187.0) * k2A
                           + (float)(64448.0 / 6561.0) * k3A - (float)(212.0 / 729.0) * k4A),
                   zB + h * ((float)(19372.0 / 6561.0) * k1B - (float)(25360.0 / 2187.0) * k2B
                           + (float)(64448.0 / 6561.0) * k3B - (float)(212.0 / 729.0) * k4B),
                   k5A, k5B);
            feval2(zA + h * ((float)(9017.0 / 3168.0) * k1A - (float)(355.0 / 33.0) * k2A
                           + (float)(46732.0 / 5247.0) * k3A + (float)(49.0 / 176.0) * k4A
                           - (float)(5103.0 / 18656.0) * k5A),
                   zB + h * ((float)(9017.0 / 3168.0) * k1B - (float)(355.0 / 33.0) * k2B
                           + (float)(46732.0 / 5247.0) * k3B + (float)(49.0 / 176.0) * k4B
                           - (float)(5103.0 / 18656.0) * k5B),
                   k6A, k6B);
            zA = zA + h * ((float)(35.0 / 384.0) * k1A + (float)(500.0 / 1113.0) * k3A
                         + (float)(125.0 / 192.0) * k4A - (float)(2187.0 / 6784.0) * k5A
                         + (float)(11.0 / 84.0) * k6A);
            zB = zB + h * ((float)(35.0 / 384.0) * k1B + (float)(500.0 / 1113.0) * k3B
                         + (float)(125.0 / 192.0) * k4B - (float)(2187.0 / 6784.0) * k5B
                         + (float)(11.0 / 84.0) * k6B);
        }
        if (tid < 16) {
            ztrajA[(l + 1) * 16 + tid] = zA;
            zdiffA[l * 16 + tid] = (zA - zsA) / dt;
        } else if (tid >= 128 && tid < 144) {
            const int t2 = tid - 128;
            ztrajB[(l + 1) * 16 + t2] = zB;
            zdiffB[l * 16 + t2] = (zB - zsB) / dt;
        }
    }
}

// ---------------------------------------------------------------------------
// Decoder: fused 3-layer MLP over 51200 rows. M-tile=16, 256 threads,
// 4 blocks/CU to hide the L2-bound w2 reads. (unchanged)
// ---------------------------------------------------------------------------
#define GS 516   // padded LDS stride for the 16x512 activation tile

__global__ __launch_bounds__(256, 4) void dec_kernel(
    const float* __restrict__ ztr,
    const float* __restrict__ w1, const float* __restrict__ b1,
    const float* __restrict__ w2, const float* __restrict__ b2,
    const float* __restrict__ w3, const float* __restrict__ b3,
    float* __restrict__ xhat)
{
    __shared__ __align__(16) float zt[16 * 17];
    __shared__ __align__(16) float g[16 * GS];

    const int t    = threadIdx.x;
    const int blk  = blockIdx.x;
    const int tr   = t >> 5;
    const int tc   = t & 31;
    const int row0 = blk * 16;
    const int r0   = 2 * tr;

    {
        int r = t >> 4, dd = t & 15;
        zt[r * 17 + dd] = ztr[(row0 + r) * 16 + dd];
    }
    __syncthreads();

    // Phase A: g1 = relu(z @ w1 + b1), K=16
    {
        float acc[2][16];
#pragma unroll
        for (int p = 0; p < 2; ++p)
#pragma unroll
            for (int i = 0; i < 16; ++i) acc[p][i] = 0.0f;

#pragma unroll
        for (int k = 0; k < 16; ++k) {
            float a0 = zt[(r0 + 0) * 17 + k];
            float a1 = zt[(r0 + 1) * 17 + k];
            const float4* wr = (const float4*)(w1 + k * 512 + 16 * tc);
#pragma unroll
            for (int u = 0; u < 4; ++u) {
                float4 wv = wr[u];
                acc[0][4 * u + 0] = fmaf(a0, wv.x, acc[0][4 * u + 0]);
                acc[0][4 * u + 1] = fmaf(a0, wv.y, acc[0][4 * u + 1]);
                acc[0][4 * u + 2] = fmaf(a0, wv.z, acc[0][4 * u + 2]);
                acc[0][4 * u + 3] = fmaf(a0, wv.w, acc[0][4 * u + 3]);
                acc[1][4 * u + 0] = fmaf(a1, wv.x, acc[1][4 * u + 0]);
                acc[1][4 * u + 1] = fmaf(a1, wv.y, acc[1][4 * u + 1]);
                acc[1][4 * u + 2] = fmaf(a1, wv.z, acc[1][4 * u + 2]);
                acc[1][4 * u + 3] = fmaf(a1, wv.w, acc[1][4 * u + 3]);
            }
        }
        const float4* bb = (const float4*)(b1 + 16 * tc);
#pragma unroll
        for (int u = 0; u < 4; ++u) {
            float4 bv = bb[u];
#pragma unroll
            for (int p = 0; p < 2; ++p) {
                g[(r0 + p) * GS + 16 * tc + 4 * u + 0] = fmaxf(acc[p][4 * u + 0] + bv.x, 0.0f);
                g[(r0 + p) * GS + 16 * tc + 4 * u + 1] = fmaxf(acc[p][4 * u + 1] + bv.y, 0.0f);
                g[(r0 + p) * GS + 16 * tc + 4 * u + 2] = fmaxf(acc[p][4 * u + 2] + bv.z, 0.0f);
                g[(r0 + p) * GS + 16 * tc + 4 * u + 3] = fmaxf(acc[p][4 * u + 3] + bv.w, 0.0f);
            }
        }
    }
    __syncthreads();

    // Phase B: g2 = relu(g1 @ w2 + b2), K=512
    {
        float accB[2][16];
#pragma unroll
        for (int p = 0; p < 2; ++p)
#pragma unroll
            for (int i = 0; i < 16; ++i) accB[p][i] = 0.0f;

        for (int k4 = 0; k4 < 128; ++k4) {
            float4 av0 = *(const float4*)&g[(r0 + 0) * GS + 4 * k4];
            float4 av1 = *(const float4*)&g[(r0 + 1) * GS + 4 * k4];
            float a0[4] = {av0.x, av0.y, av0.z, av0.w};
            float a1[4] = {av1.x, av1.y, av1.z, av1.w};
#pragma unroll
            for (int u = 0; u < 4; ++u) {
                const float4* wr = (const float4*)(w2 + (4 * k4 + u) * 512 + 16 * tc);
#pragma unroll
                for (int q = 0; q < 4; ++q) {
                    float4 wv = wr[q];
                    accB[0][4 * q + 0] = fmaf(a0[u], wv.x, accB[0][4 * q + 0]);
                    accB[0][4 * q + 1] = fmaf(a0[u], wv.y, accB[0][4 * q + 1]);
                    accB[0][4 * q + 2] = fmaf(a0[u], wv.z, accB[0][4 * q + 2]);
                    accB[0][4 * q + 3] = fmaf(a0[u], wv.w, accB[0][4 * q + 3]);
                    accB[1][4 * q + 0] = fmaf(a1[u], wv.x, accB[1][4 * q + 0]);
                    accB[1][4 * q + 1] = fmaf(a1[u], wv.y, accB[1][4 * q + 1]);
                    accB[1][4 * q + 2] = fmaf(a1[u], wv.z, accB[1][4 * q + 2]);
                    accB[1][4 * q + 3] = fmaf(a1[u], wv.w, accB[1][4 * q + 3]);
                }
            }
        }
        __syncthreads();
        const float4* bb = (const float4*)(b2 + 16 * tc);
#pragma unroll
        for (int u = 0; u < 4; ++u) {
            float4 bv = bb[u];
#pragma unroll
            for (int p = 0; p < 2; ++p) {
                g[(r0 + p) * GS + 16 * tc + 4 * u + 0] = fmaxf(accB[p][4 * u + 0] + bv.x, 0.0f);
                g[(r0 + p) * GS + 16 * tc + 4 * u + 1] = fmaxf(accB[p][4 * u + 1] + bv.y, 0.0f);
                g[(r0 + p) * GS + 16 * tc + 4 * u + 2] = fmaxf(accB[p][4 * u + 2] + bv.z, 0.0f);
                g[(r0 + p) * GS + 16 * tc + 4 * u + 3] = fmaxf(accB[p][4 * u + 3] + bv.w, 0.0f);
            }
        }
    }
    __syncthreads();

    // Phase C: xhat = g2 @ w3 + b3, N=256 (8 cols/thread), K=512
    {
        float accC[2][8];
#pragma unroll
        for (int p = 0; p < 2; ++p)
#pragma unroll
            for (int i = 0; i < 8; ++i) accC[p][i] = 0.0f;

        for (int k4 = 0; k4 < 128; ++k4) {
            float4 av0 = *(const float4*)&g[(r0 + 0) * GS + 4 * k4];
            float4 av1 = *(const float4*)&g[(r0 + 1) * GS + 4 * k4];
            float a0[4] = {av0.x, av0.y, av0.z, av0.w};
            float a1[4] = {av1.x, av1.y, av1.z, av1.w};
#pragma unroll
            for (int u = 0; u < 4; ++u) {
                const float4* wr = (const float4*)(w3 + (4 * k4 + u) * 256 + 8 * tc);
                float4 w0 = wr[0], w1v = wr[1];
                accC[0][0] = fmaf(a0[u], w0.x,  accC[0][0]);
                accC[0][1] = fmaf(a0[u], w0.y,  accC[0][1]);
                accC[0][2] = fmaf(a0[u], w0.z,  accC[0][2]);
                accC[0][3] = fmaf(a0[u], w0.w,  accC[0][3]);
                accC[0][4] = fmaf(a0[u], w1v.x, accC[0][4]);
                accC[0][5] = fmaf(a0[u], w1v.y, accC[0][5]);
                accC[0][6] = fmaf(a0[u], w1v.z, accC[0][6]);
                accC[0][7] = fmaf(a0[u], w1v.w, accC[0][7]);
                accC[1][0] = fmaf(a1[u], w0.x,  accC[1][0]);
                accC[1][1] = fmaf(a1[u], w0.y,  accC[1][1]);
                accC[1][2] = fmaf(a1[u], w0.z,  accC[1][2]);
                accC[1][3] = fmaf(a1[u], w0.w,  accC[1][3]);
                accC[1][4] = fmaf(a1[u], w1v.x, accC[1][4]);
                accC[1][5] = fmaf(a1[u], w1v.y, accC[1][5]);
                accC[1][6] = fmaf(a1[u], w1v.z, accC[1][6]);
                accC[1][7] = fmaf(a1[u], w1v.w, accC[1][7]);
            }
        }
        const float4* bb = (const float4*)(b3 + 8 * tc);
        float4 bv0 = bb[0], bv1 = bb[1];
#pragma unroll
        for (int p = 0; p < 2; ++p) {
            float4 o0 = make_float4(accC[p][0] + bv0.x, accC[p][1] + bv0.y,
                                    accC[p][2] + bv0.z, accC[p][3] + bv0.w);
            float4 o1 = make_float4(accC[p][4] + bv1.x, accC[p][5] + bv1.y,
                                    accC[p][6] + bv1.z, accC[p][7] + bv1.w);
            float* dst = xhat + (size_t)(row0 + r0 + p) * 256 + 8 * tc;
            *(float4*)(dst)     = o0;
            *(float4*)(dst + 4) = o1;
        }
    }
}

extern "C" void kernel_launch(void* const* d_in, const int* in_sizes, int n_in,
                              void* d_out, int out_size, void* d_ws, size_t ws_size,
                              hipStream_t stream) {
    const float* x_seq  = (const float*)d_in[0];
    const float* tvec   = (const float*)d_in[1];
    const float* eps    = (const float*)d_in[2];
    const float* enc_w1 = (const float*)d_in[3];
    const float* enc_b1 = (const float*)d_in[4];
    const float* enc_w2 = (const float*)d_in[5];
    const float* enc_b2 = (const float*)d_in[6];
    const float* enc_w3 = (const float*)d_in[7];
    const float* enc_b3 = (const float*)d_in[8];
    const float* mu_w   = (const float*)d_in[9];
    const float* mu_b   = (const float*)d_in[10];
    const float* lv_w   = (const float*)d_in[11];
    const float* lv_b   = (const float*)d_in[12];
    const float* ode_w1 = (const float*)d_in[13];
    const float* ode_b1 = (const float*)d_in[14];
    const float* ode_w2 = (const float*)d_in[15];
    const float* ode_b2 = (const float*)d_in[16];
    const float* ode_w3 = (const float*)d_in[17];
    const float* ode_b3 = (const float*)d_in[18];
    const float* ln_g   = (const float*)d_in[19];
    const float* ln_b   = (const float*)d_in[20];
    const float* dec_w1 = (const float*)d_in[21];
    const float* dec_b1 = (const float*)d_in[22];
    const float* dec_w2 = (const float*)d_in[23];
    const float* dec_b2 = (const float*)d_in[24];
    const float* dec_w3 = (const float*)d_in[25];
    const float* dec_b3 = (const float*)d_in[26];
    float* out = (float*)d_out;

    enc_kernel<<<256, 256, 0, stream>>>(x_seq, eps, enc_w1, enc_b1, enc_w2, enc_b2,
                                        enc_w3, enc_b3, mu_w, mu_b, lv_w, lv_b, out);
    ode_kernel<<<128, 256, 0, stream>>>(tvec, ode_w1, ode_b1, ode_w2, ode_b2,
                                        ode_w3, ode_b3, ln_g, ln_b, out);
    dec_kernel<<<3200, 256, 0, stream>>>(out + OFF_ZT, dec_w1, dec_b1, dec_w2, dec_b2,
                                         dec_w3, dec_b3, out);
}

// Round 10
// 10723.698 us; speedup vs baseline: 1.1813x; 1.1813x over previous
//
#include <hip/hip_runtime.h>

// Output layout (flat f32, reference return order):
//   xhat  : B*L*N   = 13,107,200  @ 0
//   mu    : B*D     =      4,096  @ 13,107,200
//   logvar: B*D     =      4,096  @ 13,111,296
//   z_traj: B*L*D   =    819,200  @ 13,115,392
//   zdiff : B*(L-1)*D =  815,104  @ 13,934,592
#define OFF_MU   13107200
#define OFF_LV   13111296
#define OFF_ZT   13115392
#define OFF_ZD   13934592

typedef float v2f __attribute__((ext_vector_type(2)));

__device__ __forceinline__ float silu_f(float x) {
    return x / (1.0f + __expf(-x));
}

__device__ __forceinline__ float readlane_f(float v, int l) {
    return __uint_as_float(__builtin_amdgcn_readlane(__float_as_uint(v), l));
}

__device__ __forceinline__ v2f fma2(v2f a, v2f b, v2f c) {
    return __builtin_elementwise_fma(a, b, c);
}

// x + dpp_move(x) with compile-time DPP control. VALU-latency cross-lane.
template <int CTRL>
__device__ __forceinline__ float dppadd(float x) {
    int y = __builtin_amdgcn_update_dpp(0, __float_as_int(x), CTRL, 0xF, 0xF, true);
    return x + __int_as_float(y);
}

// Sum of x over each 16-lane row (values replicated per row afterwards).
__device__ __forceinline__ float sum16_dpp(float x) {
    x = dppadd<0xB1>(x);    // quad_perm xor1
    x = dppadd<0x4E>(x);    // quad_perm xor2
    x = dppadd<0x141>(x);   // row_half_mirror (xor4 once quad-uniform)
    x = dppadd<0x140>(x);   // row_mirror (xor8 once 8-uniform)
    return x;
}

// ---------------------------------------------------------------------------
// Encoder: one block per batch row. x0(256) -> 512 -> 256 -> 128 -> mu/lv(16)
// (unchanged — negligible cost)
// ---------------------------------------------------------------------------
__global__ __launch_bounds__(256) void enc_kernel(
    const float* __restrict__ xseq, const float* __restrict__ eps,
    const float* __restrict__ w1, const float* __restrict__ b1,
    const float* __restrict__ w2, const float* __restrict__ b2,
    const float* __restrict__ w3, const float* __restrict__ b3,
    const float* __restrict__ muw, const float* __restrict__ mub,
    const float* __restrict__ lvw, const float* __restrict__ lvb,
    float* __restrict__ out)
{
    __shared__ float xr[256];
    __shared__ float h1[512];
    __shared__ float h2[256];
    __shared__ float h3[128];

    const int t = threadIdx.x;
    const int b = blockIdx.x;

    xr[t] = xseq[b * (200 * 256) + t];
    __syncthreads();

    {
        float acc0 = b1[t], acc1 = b1[t + 256];
        for (int i = 0; i < 256; ++i) {
            float xv = xr[i];
            acc0 = fmaf(xv, w1[i * 512 + t],       acc0);
            acc1 = fmaf(xv, w1[i * 512 + t + 256], acc1);
        }
        h1[t]       = fmaxf(acc0, 0.0f);
        h1[t + 256] = fmaxf(acc1, 0.0f);
    }
    __syncthreads();

    {
        float acc = b2[t];
        for (int i = 0; i < 512; ++i) acc = fmaf(h1[i], w2[i * 256 + t], acc);
        h2[t] = fmaxf(acc, 0.0f);
    }
    __syncthreads();

    if (t < 128) {
        float acc = b3[t];
        for (int i = 0; i < 256; ++i) acc = fmaf(h2[i], w3[i * 128 + t], acc);
        h3[t] = fmaxf(acc, 0.0f);
    }
    __syncthreads();

    if (t < 16) {
        float mu = mub[t], lv = lvb[t];
        for (int i = 0; i < 128; ++i) {
            float hv = h3[i];
            mu = fmaf(hv, muw[i * 16 + t], mu);
            lv = fmaf(hv, lvw[i * 16 + t], lv);
        }
        out[OFF_MU + b * 16 + t] = mu;
        out[OFF_LV + b * 16 + t] = lv;
        float z0 = mu + __expf(0.5f * lv) * eps[b * 16 + t];
        out[OFF_ZT + b * 3200 + t] = z0;
    }
}

// ---------------------------------------------------------------------------
// ODE integrator v10: 8 waves/block, TWO elements: A = waves 0-3, B = 4-7.
//   Each wave runs exactly v8's K-split-4 code (issue ~580 cyc, 84 VGPR) for
//   its own element; each SIMD hosts one A-wave + one B-wave -> hardware
//   SMT fills every stall with the sibling's instructions.
//   Barrier count reduced to ONE per feval: the combine is computed
//   redundantly per-wave into a wave-private a2 buffer (8 conflict-free
//   ds_read_b32 + 2 silu), so the only cross-wave traffic is `part`,
//   protected by the barrier + parity double-buffer.
//   Race audit: readers of part[p] (feval N combine, right after barrier N)
//   finish before barrier N+1; the next writer of part[p] (feval N+2 L2)
//   writes only after barrier N+1 — safe with one barrier per feval.
// ---------------------------------------------------------------------------
__global__ __launch_bounds__(512, 1) void ode_kernel(
    const float* __restrict__ tvec,
    const float* __restrict__ ow1, const float* __restrict__ ob1,
    const float* __restrict__ ow2, const float* __restrict__ ob2,
    const float* __restrict__ ow3, const float* __restrict__ ob3,
    const float* __restrict__ lng, const float* __restrict__ lnb,
    float* __restrict__ out)
{
    __shared__ __align__(16) float a1s[2][4][32];    // [elem][kq][col] wave-private
    __shared__ __align__(16) float part[2][2][512];  // [parity][elem][kq*128+col]
    __shared__ __align__(16) float a2w[2][4][128];   // [elem][kq][col] wave-private
    __shared__ __align__(16) float p3s[2][4][64];    // [elem][kq][..]  wave-private

    const int tid  = threadIdx.x;
    const int wv   = tid >> 6;       // wave id 0..7
    const int e    = wv >> 2;        // element 0/1
    const int kq   = wv & 3;         // K-quarter within element
    const int lane = tid & 63;
    const int b    = blockIdx.x;     // 0..127
    const int d    = lane & 15;      // owned z-dim (replicated x4 per wave)
    const int g    = lane >> 4;      // L3 K-chunk group
    const int c0   = lane, c1 = lane + 64;      // L2 output columns
    const int col1 = 32 * kq + (lane & 31);     // L1 column (lanes<32 write)

    // ---- register-resident weights via volatile (loaded exactly once) -----
    const volatile float* vw1 = ow1;
    const volatile float* vw2 = ow2;
    const volatile float* vw3 = ow3;

    float w1r[16];
#pragma unroll
    for (int k = 0; k < 16; ++k) w1r[k] = vw1[k * 128 + col1];

    v2f w2r0[16], w2r1[16];          // K-quarter kq, cols c0/c1, K-pairs
#pragma unroll
    for (int q = 0; q < 16; ++q) {
        int k0 = 32 * kq + 2 * q;
        v2f t0 = { vw2[k0 * 128 + c0], vw2[(k0 + 1) * 128 + c0] };
        v2f t1 = { vw2[k0 * 128 + c1], vw2[(k0 + 1) * 128 + c1] };
        w2r0[q] = t0;
        w2r1[q] = t1;
    }
    v2f w3r[16];   // K-chunk g (32 wide), stored in bank-staggered read order
#pragma unroll
    for (int qq = 0; qq < 8; ++qq) {
        int qsel = (qq + 2 * g) & 7;
        int k0   = 32 * g + 4 * qsel;
        v2f t0 = { vw3[(k0 + 0) * 16 + d], vw3[(k0 + 1) * 16 + d] };
        v2f t1 = { vw3[(k0 + 2) * 16 + d], vw3[(k0 + 3) * 16 + d] };
        w3r[2 * qq]     = t0;
        w3r[2 * qq + 1] = t1;
    }
    const volatile float* vb1 = ob1;
    const volatile float* vb2 = ob2;
    const volatile float* vb3 = ob3;
    const volatile float* vlg = lng;
    const volatile float* vlb = lnb;
    const float b1c  = vb1[col1];
    const float b2c0 = vb2[c0], b2c1 = vb2[c1];
    const float b3d  = vb3[d];
    const float lngd = vlg[d], lnbd = vlb[d];

    float* ztraj = out + OFF_ZT + (2 * b + e) * 3200;   // this element's
    float* zdiff = out + OFF_ZD + (2 * b + e) * 3184;

    float z = ztraj[d];              // z0, replicated in this element's waves

    // one evaluation of f(za) for THIS wave's element; p = parity.
    auto feval = [&](float za, int p) -> float {
        // L1: this wave's 32 a1 columns. zarg via readlane -> SGPR.
        float ae = 0.0f, ao = 0.0f;
#pragma unroll
        for (int k = 0; k < 16; k += 2) {
            float zk0 = readlane_f(za, k);
            float zk1 = readlane_f(za, k + 1);
            ae = fmaf(zk0, w1r[k],     ae);
            ao = fmaf(zk1, w1r[k + 1], ao);
        }
        if (lane < 32) a1s[e][kq][lane] = silu_f(ae + ao + b1c);
        // intra-wave write->read: compiler inserts lgkmcnt

        // L2 partial: K-range [32kq,32kq+32), 2 cols/lane.
        v2f A  = {0.0f, 0.0f}, Ab = {0.0f, 0.0f};
        v2f B  = {0.0f, 0.0f}, Bb = {0.0f, 0.0f};
        const float4* a14 = (const float4*)a1s[e][kq];
#pragma unroll
        for (int i = 0; i < 8; ++i) {
            float4 av = a14[i];
            v2f plo = { av.x, av.y };
            v2f phi = { av.z, av.w };
            A  = fma2(plo, w2r0[2 * i],     A);
            Ab = fma2(phi, w2r0[2 * i + 1], Ab);
            B  = fma2(plo, w2r1[2 * i],     B);
            Bb = fma2(phi, w2r1[2 * i + 1], Bb);
        }
        part[p][e][kq * 128 + c0] = A.x + A.y + Ab.x + Ab.y;
        part[p][e][kq * 128 + c1] = B.x + B.y + Bb.x + Bb.y;
        __syncthreads();                     // the ONE barrier per feval

        // combine (redundant per wave, wave-private result): 2 cols/lane,
        // 8 lane-consecutive ds_read_b32 — conflict-free.
        {
            float s0 = part[p][e][c0] + part[p][e][128 + c0]
                     + part[p][e][256 + c0] + part[p][e][384 + c0] + b2c0;
            float s1 = part[p][e][c1] + part[p][e][128 + c1]
                     + part[p][e][256 + c1] + part[p][e][384 + c1] + b2c1;
            a2w[e][kq][c0 & 127] = silu_f(s0);
            a2w[e][kq][c1 & 127] = silu_f(s1);
        }
        // intra-wave write->read

        // L3: output d, K-chunk g (32 wide), bank-staggered broadcast b128.
        v2f pp = {0.0f, 0.0f};
#pragma unroll
        for (int qq = 0; qq < 8; ++qq) {
            int qsel = (qq + 2 * g) & 7;
            float4 av = *(const float4*)&a2w[e][kq][32 * g + 4 * qsel];
            pp = fma2((v2f){ av.x, av.y }, w3r[2 * qq],     pp);
            pp = fma2((v2f){ av.z, av.w }, w3r[2 * qq + 1], pp);
        }
        // cross-group combine via wave-private LDS (one round trip)
        p3s[e][kq][lane] = pp.x + pp.y;
        float dz = b3d + p3s[e][kq][d] + p3s[e][kq][d + 16]
                       + p3s[e][kq][d + 32] + p3s[e][kq][d + 48];

        // One-pass LayerNorm: Σdz and Σdz² as independent DPP chains.
        float s1 = sum16_dpp(dz);
        float s2 = sum16_dpp(dz * dz);
        float m  = s1 * 0.0625f;
        float v  = fmaf(m, -m, s2 * 0.0625f);
        return (dz - m) * rsqrtf(v + 1e-5f) * lngd + lnbd;
    };

    for (int l = 0; l < 199; ++l) {
        const float dt = tvec[l + 1] - tvec[l];
        const float h  = dt * 0.125f;          // dt / K, K=8 (exact)
        const float zstart = z;
        for (int s = 0; s < 8; ++s) {
            // parities 0,1,0,1,0,1 (even count per substep)
            float k1 = feval(z, 0);
            float k2 = feval(z + h * (k1 * (float)(1.0 / 5.0)), 1);
            float k3 = feval(z + h * ((float)(3.0 / 40.0) * k1 + (float)(9.0 / 40.0) * k2), 0);
            float k4 = feval(z + h * ((float)(44.0 / 45.0) * k1 - (float)(56.0 / 15.0) * k2
                                    + (float)(32.0 / 9.0) * k3), 1);
            float k5 = feval(z + h * ((float)(19372.0 / 6561.0) * k1 - (float)(25360.0 / 2187.0) * k2
                                    + (float)(64448.0 / 6561.0) * k3 - (float)(212.0 / 729.0) * k4), 0);
            float k6 = feval(z + h * ((float)(9017.0 / 3168.0) * k1 - (float)(355.0 / 33.0) * k2
                                    + (float)(46732.0 / 5247.0) * k3 + (float)(49.0 / 176.0) * k4
                                    - (float)(5103.0 / 18656.0) * k5), 1);
            z = z + h * ((float)(35.0 / 384.0) * k1 + (float)(500.0 / 1113.0) * k3
                       + (float)(125.0 / 192.0) * k4 - (float)(2187.0 / 6784.0) * k5
                       + (float)(11.0 / 84.0) * k6);
        }
        if (kq == 0 && lane < 16) {          // wave 0 -> elem A, wave 4 -> elem B
            ztraj[(l + 1) * 16 + lane] = z;
            zdiff[l * 16 + lane] = (z - zstart) / dt;
        }
    }
}

// ---------------------------------------------------------------------------
// Decoder: fused 3-layer MLP over 51200 rows. M-tile=16, 256 threads,
// 4 blocks/CU to hide the L2-bound w2 reads. (unchanged)
// ---------------------------------------------------------------------------
#define GS 516   // padded LDS stride for the 16x512 activation tile

__global__ __launch_bounds__(256, 4) void dec_kernel(
    const float* __restrict__ ztr,
    const float* __restrict__ w1, const float* __restrict__ b1,
    const float* __restrict__ w2, const float* __restrict__ b2,
    const float* __restrict__ w3, const float* __restrict__ b3,
    float* __restrict__ xhat)
{
    __shared__ __align__(16) float zt[16 * 17];
    __shared__ __align__(16) float g[16 * GS];

    const int t    = threadIdx.x;
    const int blk  = blockIdx.x;
    const int tr   = t >> 5;
    const int tc   = t & 31;
    const int row0 = blk * 16;
    const int r0   = 2 * tr;

    {
        int r = t >> 4, dd = t & 15;
        zt[r * 17 + dd] = ztr[(row0 + r) * 16 + dd];
    }
    __syncthreads();

    // Phase A: g1 = relu(z @ w1 + b1), K=16
    {
        float acc[2][16];
#pragma unroll
        for (int p = 0; p < 2; ++p)
#pragma unroll
            for (int i = 0; i < 16; ++i) acc[p][i] = 0.0f;

#pragma unroll
        for (int k = 0; k < 16; ++k) {
            float a0 = zt[(r0 + 0) * 17 + k];
            float a1 = zt[(r0 + 1) * 17 + k];
            const float4* wr = (const float4*)(w1 + k * 512 + 16 * tc);
#pragma unroll
            for (int u = 0; u < 4; ++u) {
                float4 wv = wr[u];
                acc[0][4 * u + 0] = fmaf(a0, wv.x, acc[0][4 * u + 0]);
                acc[0][4 * u + 1] = fmaf(a0, wv.y, acc[0][4 * u + 1]);
                acc[0][4 * u + 2] = fmaf(a0, wv.z, acc[0][4 * u + 2]);
                acc[0][4 * u + 3] = fmaf(a0, wv.w, acc[0][4 * u + 3]);
                acc[1][4 * u + 0] = fmaf(a1, wv.x, acc[1][4 * u + 0]);
                acc[1][4 * u + 1] = fmaf(a1, wv.y, acc[1][4 * u + 1]);
                acc[1][4 * u + 2] = fmaf(a1, wv.z, acc[1][4 * u + 2]);
                acc[1][4 * u + 3] = fmaf(a1, wv.w, acc[1][4 * u + 3]);
            }
        }
        const float4* bb = (const float4*)(b1 + 16 * tc);
#pragma unroll
        for (int u = 0; u < 4; ++u) {
            float4 bv = bb[u];
#pragma unroll
            for (int p = 0; p < 2; ++p) {
                g[(r0 + p) * GS + 16 * tc + 4 * u + 0] = fmaxf(acc[p][4 * u + 0] + bv.x, 0.0f);
                g[(r0 + p) * GS + 16 * tc + 4 * u + 1] = fmaxf(acc[p][4 * u + 1] + bv.y, 0.0f);
                g[(r0 + p) * GS + 16 * tc + 4 * u + 2] = fmaxf(acc[p][4 * u + 2] + bv.z, 0.0f);
                g[(r0 + p) * GS + 16 * tc + 4 * u + 3] = fmaxf(acc[p][4 * u + 3] + bv.w, 0.0f);
            }
        }
    }
    __syncthreads();

    // Phase B: g2 = relu(g1 @ w2 + b2), K=512
    {
        float accB[2][16];
#pragma unroll
        for (int p = 0; p < 2; ++p)
#pragma unroll
            for (int i = 0; i < 16; ++i) accB[p][i] = 0.0f;

        for (int k4 = 0; k4 < 128; ++k4) {
            float4 av0 = *(const float4*)&g[(r0 + 0) * GS + 4 * k4];
            float4 av1 = *(const float4*)&g[(r0 + 1) * GS + 4 * k4];
            float a0[4] = {av0.x, av0.y, av0.z, av0.w};
            float a1[4] = {av1.x, av1.y, av1.z, av1.w};
#pragma unroll
            for (int u = 0; u < 4; ++u) {
                const float4* wr = (const float4*)(w2 + (4 * k4 + u) * 512 + 16 * tc);
#pragma unroll
                for (int q = 0; q < 4; ++q) {
                    float4 wv = wr[q];
                    accB[0][4 * q + 0] = fmaf(a0[u], wv.x, accB[0][4 * q + 0]);
                    accB[0][4 * q + 1] = fmaf(a0[u], wv.y, accB[0][4 * q + 1]);
                    accB[0][4 * q + 2] = fmaf(a0[u], wv.z, accB[0][4 * q + 2]);
                    accB[0][4 * q + 3] = fmaf(a0[u], wv.w, accB[0][4 * q + 3]);
                    accB[1][4 * q + 0] = fmaf(a1[u], wv.x, accB[1][4 * q + 0]);
                    accB[1][4 * q + 1] = fmaf(a1[u], wv.y, accB[1][4 * q + 1]);
                    accB[1][4 * q + 2] = fmaf(a1[u], wv.z, accB[1][4 * q + 2]);
                    accB[1][4 * q + 3] = fmaf(a1[u], wv.w, accB[1][4 * q + 3]);
                }
            }
        }
        __syncthreads();
        const float4* bb = (const float4*)(b2 + 16 * tc);
#pragma unroll
        for (int u = 0; u < 4; ++u) {
            float4 bv = bb[u];
#pragma unroll
            for (int p = 0; p < 2; ++p) {
                g[(r0 + p) * GS + 16 * tc + 4 * u + 0] = fmaxf(accB[p][4 * u + 0] + bv.x, 0.0f);
                g[(r0 + p) * GS + 16 * tc + 4 * u + 1] = fmaxf(accB[p][4 * u + 1] + bv.y, 0.0f);
                g[(r0 + p) * GS + 16 * tc + 4 * u + 2] = fmaxf(accB[p][4 * u + 2] + bv.z, 0.0f);
                g[(r0 + p) * GS + 16 * tc + 4 * u + 3] = fmaxf(accB[p][4 * u + 3] + bv.w, 0.0f);
            }
        }
    }
    __syncthreads();

    // Phase C: xhat = g2 @ w3 + b3, N=256 (8 cols/thread), K=512
    {
        float accC[2][8];
#pragma unroll
        for (int p = 0; p < 2; ++p)
#pragma unroll
            for (int i = 0; i < 8; ++i) accC[p][i] = 0.0f;

        for (int k4 = 0; k4 < 128; ++k4) {
            float4 av0 = *(const float4*)&g[(r0 + 0) * GS + 4 * k4];
            float4 av1 = *(const float4*)&g[(r0 + 1) * GS + 4 * k4];
            float a0[4] = {av0.x, av0.y, av0.z, av0.w};
            float a1[4] = {av1.x, av1.y, av1.z, av1.w};
#pragma unroll
            for (int u = 0; u < 4; ++u) {
                const float4* wr = (const float4*)(w3 + (4 * k4 + u) * 256 + 8 * tc);
                float4 w0 = wr[0], w1v = wr[1];
                accC[0][0] = fmaf(a0[u], w0.x,  accC[0][0]);
                accC[0][1] = fmaf(a0[u], w0.y,  accC[0][1]);
                accC[0][2] = fmaf(a0[u], w0.z,  accC[0][2]);
                accC[0][3] = fmaf(a0[u], w0.w,  accC[0][3]);
                accC[0][4] = fmaf(a0[u], w1v.x, accC[0][4]);
                accC[0][5] = fmaf(a0[u], w1v.y, accC[0][5]);
                accC[0][6] = fmaf(a0[u], w1v.z, accC[0][6]);
                accC[0][7] = fmaf(a0[u], w1v.w, accC[0][7]);
                accC[1][0] = fmaf(a1[u], w0.x,  accC[1][0]);
                accC[1][1] = fmaf(a1[u], w0.y,  accC[1][1]);
                accC[1][2] = fmaf(a1[u], w0.z,  accC[1][2]);
                accC[1][3] = fmaf(a1[u], w0.w,  accC[1][3]);
                accC[1][4] = fmaf(a1[u], w1v.x, accC[1][4]);
                accC[1][5] = fmaf(a1[u], w1v.y, accC[1][5]);
                accC[1][6] = fmaf(a1[u], w1v.z, accC[1][6]);
                accC[1][7] = fmaf(a1[u], w1v.w, accC[1][7]);
            }
        }
        const float4* bb = (const float4*)(b3 + 8 * tc);
        float4 bv0 = bb[0], bv1 = bb[1];
#pragma unroll
        for (int p = 0; p < 2; ++p) {
            float4 o0 = make_float4(accC[p][0] + bv0.x, accC[p][1] + bv0.y,
                                    accC[p][2] + bv0.z, accC[p][3] + bv0.w);
            float4 o1 = make_float4(accC[p][4] + bv1.x, accC[p][5] + bv1.y,
                                    accC[p][6] + bv1.z, accC[p][7] + bv1.w);
            float* dst = xhat + (size_t)(row0 + r0 + p) * 256 + 8 * tc;
            *(float4*)(dst)     = o0;
            *(float4*)(dst + 4) = o1;
        }
    }
}

extern "C" void kernel_launch(void* const* d_in, const int* in_sizes, int n_in,
                              void* d_out, int out_size, void* d_ws, size_t ws_size,
                              hipStream_t stream) {
    const float* x_seq  = (const float*)d_in[0];
    const float* tvec   = (const float*)d_in[1];
    const float* eps    = (const float*)d_in[2];
    const float* enc_w1 = (const float*)d_in[3];
    const float* enc_b1 = (const float*)d_in[4];
    const float* enc_w2 = (const float*)d_in[5];
    const float* enc_b2 = (const float*)d_in[6];
    const float* enc_w3 = (const float*)d_in[7];
    const float* enc_b3 = (const float*)d_in[8];
    const float* mu_w   = (const float*)d_in[9];
    const float* mu_b   = (const float*)d_in[10];
    const float* lv_w   = (const float*)d_in[11];
    const float* lv_b   = (const float*)d_in[12];
    const float* ode_w1 = (const float*)d_in[13];
    const float* ode_b1 = (const float*)d_in[14];
    const float* ode_w2 = (const float*)d_in[15];
    const float* ode_b2 = (const float*)d_in[16];
    const float* ode_w3 = (const float*)d_in[17];
    const float* ode_b3 = (const float*)d_in[18];
    const float* ln_g   = (const float*)d_in[19];
    const float* ln_b   = (const float*)d_in[20];
    const float* dec_w1 = (const float*)d_in[21];
    const float* dec_b1 = (const float*)d_in[22];
    const float* dec_w2 = (const float*)d_in[23];
    const float* dec_b2 = (const float*)d_in[24];
    const float* dec_w3 = (const float*)d_in[25];
    const float* dec_b3 = (const float*)d_in[26];
    float* out = (float*)d_out;

    enc_kernel<<<256, 256, 0, stream>>>(x_seq, eps, enc_w1, enc_b1, enc_w2, enc_b2,
                                        enc_w3, enc_b3, mu_w, mu_b, lv_w, lv_b, out);
    ode_kernel<<<128, 512, 0, stream>>>(tvec, ode_w1, ode_b1, ode_w2, ode_b2,
                                        ode_w3, ode_b3, ln_g, ln_b, out);
    dec_kernel<<<3200, 256, 0, stream>>>(out + OFF_ZT, dec_w1, dec_b1, dec_w2, dec_b2,
                                         dec_w3, dec_b3, out);
}

// Round 11
// 9107.825 us; speedup vs baseline: 1.3908x; 1.1774x over previous
//
#include <hip/hip_runtime.h>

// Output layout (flat f32, reference return order):
//   xhat  : B*L*N   = 13,107,200  @ 0
//   mu    : B*D     =      4,096  @ 13,107,200
//   logvar: B*D     =      4,096  @ 13,111,296
//   z_traj: B*L*D   =    819,200  @ 13,115,392
//   zdiff : B*(L-1)*D =  815,104  @ 13,934,592
#define OFF_MU   13107200
#define OFF_LV   13111296
#define OFF_ZT   13115392
#define OFF_ZD   13934592

typedef float v2f __attribute__((ext_vector_type(2)));

__device__ __forceinline__ float silu_f(float x) {
    return x / (1.0f + __expf(-x));
}

__device__ __forceinline__ float readlane_f(float v, int l) {
    return __uint_as_float(__builtin_amdgcn_readlane(__float_as_uint(v), l));
}

__device__ __forceinline__ v2f fma2(v2f a, v2f b, v2f c) {
    return __builtin_elementwise_fma(a, b, c);
}

// x + dpp_move(x) with compile-time DPP control. VALU-latency cross-lane.
template <int CTRL>
__device__ __forceinline__ float dppadd(float x) {
    int y = __builtin_amdgcn_update_dpp(0, __float_as_int(x), CTRL, 0xF, 0xF, true);
    return x + __int_as_float(y);
}

// Sum of x over each 16-lane row (values replicated per row afterwards).
__device__ __forceinline__ float sum16_dpp(float x) {
    x = dppadd<0xB1>(x);    // quad_perm xor1
    x = dppadd<0x4E>(x);    // quad_perm xor2
    x = dppadd<0x141>(x);   // row_half_mirror (xor4 once quad-uniform)
    x = dppadd<0x140>(x);   // row_mirror (xor8 once 8-uniform)
    return x;
}

// ---------------------------------------------------------------------------
// Encoder: one block per batch row. x0(256) -> 512 -> 256 -> 128 -> mu/lv(16)
// (unchanged — negligible cost)
// ---------------------------------------------------------------------------
__global__ __launch_bounds__(256) void enc_kernel(
    const float* __restrict__ xseq, const float* __restrict__ eps,
    const float* __restrict__ w1, const float* __restrict__ b1,
    const float* __restrict__ w2, const float* __restrict__ b2,
    const float* __restrict__ w3, const float* __restrict__ b3,
    const float* __restrict__ muw, const float* __restrict__ mub,
    const float* __restrict__ lvw, const float* __restrict__ lvb,
    float* __restrict__ out)
{
    __shared__ float xr[256];
    __shared__ float h1[512];
    __shared__ float h2[256];
    __shared__ float h3[128];

    const int t = threadIdx.x;
    const int b = blockIdx.x;

    xr[t] = xseq[b * (200 * 256) + t];
    __syncthreads();

    {
        float acc0 = b1[t], acc1 = b1[t + 256];
        for (int i = 0; i < 256; ++i) {
            float xv = xr[i];
            acc0 = fmaf(xv, w1[i * 512 + t],       acc0);
            acc1 = fmaf(xv, w1[i * 512 + t + 256], acc1);
        }
        h1[t]       = fmaxf(acc0, 0.0f);
        h1[t + 256] = fmaxf(acc1, 0.0f);
    }
    __syncthreads();

    {
        float acc = b2[t];
        for (int i = 0; i < 512; ++i) acc = fmaf(h1[i], w2[i * 256 + t], acc);
        h2[t] = fmaxf(acc, 0.0f);
    }
    __syncthreads();

    if (t < 128) {
        float acc = b3[t];
        for (int i = 0; i < 256; ++i) acc = fmaf(h2[i], w3[i * 128 + t], acc);
        h3[t] = fmaxf(acc, 0.0f);
    }
    __syncthreads();

    if (t < 16) {
        float mu = mub[t], lv = lvb[t];
        for (int i = 0; i < 128; ++i) {
            float hv = h3[i];
            mu = fmaf(hv, muw[i * 16 + t], mu);
            lv = fmaf(hv, lvw[i * 16 + t], lv);
        }
        out[OFF_MU + b * 16 + t] = mu;
        out[OFF_LV + b * 16 + t] = lv;
        float z0 = mu + __expf(0.5f * lv) * eps[b * 16 + t];
        out[OFF_ZT + b * 3200 + t] = z0;
    }
}

// ---------------------------------------------------------------------------
// ODE integrator v11: v8 skeleton (256 blocks, 4 waves, K-split-4) + two
// latency cuts:
//   1) ONE barrier per feval: parity-double-buffered `part` + redundant
//      per-wave combine into wave-private a2w (v10's proven scheme).
//   2) a1 kept in REGISTERS; L2 reads it via v_readlane->SGPR (wave kq's L2
//      needs exactly the a1 chunk it computed: cols 32kq..32kq+32, present
//      in lanes 0..31 / duplicated 32..63). No a1 LDS round trip.
//   Race audit (single barrier, parity p): readers of part[p] (combine of
//   feval N, after barrier N) finish before barrier N+1; next writer of
//   part[p] is feval N+2's L2, after barrier N+1 — safe.
// ---------------------------------------------------------------------------
__global__ __launch_bounds__(256, 1) void ode_kernel(
    const float* __restrict__ tvec,
    const float* __restrict__ ow1, const float* __restrict__ ob1,
    const float* __restrict__ ow2, const float* __restrict__ ob2,
    const float* __restrict__ ow3, const float* __restrict__ ob3,
    const float* __restrict__ lng, const float* __restrict__ lnb,
    float* __restrict__ out)
{
    __shared__ __align__(16) float part[2][4 * 128];  // [parity][kq*128+col]
    __shared__ __align__(16) float a2w[4][128];       // wave-private combine
    __shared__ __align__(16) float p3s[4][64];        // wave-private L3 partials

    const int tid  = threadIdx.x;
    const int kq   = tid >> 6;       // wave id 0..3 = K-quarter
    const int lane = tid & 63;
    const int b    = blockIdx.x;
    const int d    = lane & 15;      // owned z-dim (replicated x4 per wave)
    const int g    = lane >> 4;      // L3 K-chunk group
    const int c0   = lane, c1 = lane + 64;      // L2 output columns
    const int col1 = 32 * kq + (lane & 31);     // L1 column (dup half-waves)

    // ---- register-resident weights via volatile (loaded exactly once) -----
    const volatile float* vw1 = ow1;
    const volatile float* vw2 = ow2;
    const volatile float* vw3 = ow3;

    float w1r[16];
#pragma unroll
    for (int k = 0; k < 16; ++k) w1r[k] = vw1[k * 128 + col1];

    float w2a[32], w2b[32];          // K-quarter kq, cols c0/c1 (scalar)
#pragma unroll
    for (int j = 0; j < 32; ++j) {
        w2a[j] = vw2[(32 * kq + j) * 128 + c0];
        w2b[j] = vw2[(32 * kq + j) * 128 + c1];
    }
    v2f w3r[16];   // K-chunk g (32 wide), stored in bank-staggered read order
#pragma unroll
    for (int qq = 0; qq < 8; ++qq) {
        int qsel = (qq + 2 * g) & 7;
        int k0   = 32 * g + 4 * qsel;
        v2f t0 = { vw3[(k0 + 0) * 16 + d], vw3[(k0 + 1) * 16 + d] };
        v2f t1 = { vw3[(k0 + 2) * 16 + d], vw3[(k0 + 3) * 16 + d] };
        w3r[2 * qq]     = t0;
        w3r[2 * qq + 1] = t1;
    }
    const volatile float* vb1 = ob1;
    const volatile float* vb2 = ob2;
    const volatile float* vb3 = ob3;
    const volatile float* vlg = lng;
    const volatile float* vlb = lnb;
    const float b1c  = vb1[col1];
    const float b2c0 = vb2[c0], b2c1 = vb2[c1];
    const float b3d  = vb3[d];
    const float lngd = vlg[d], lnbd = vlb[d];

    float* ztraj = out + OFF_ZT + b * 3200;   // [200][16]
    float* zdiff = out + OFF_ZD + b * 3184;   // [199][16]

    float z = ztraj[d];                       // z0, replicated, all waves

    // one evaluation of f(za); za = zarg[d] per lane (replicated x4).
    // p = compile-time parity selecting the part buffer.
    auto feval = [&](float za, int p) -> float {
        // L1: this wave's column col1. zarg broadcast via readlane -> SGPR.
        float ae = 0.0f, ao = 0.0f;
#pragma unroll
        for (int k = 0; k < 16; k += 2) {
            float zk0 = readlane_f(za, k);
            float zk1 = readlane_f(za, k + 1);
            ae = fmaf(zk0, w1r[k],     ae);
            ao = fmaf(zk1, w1r[k + 1], ao);
        }
        float a1v = silu_f(ae + ao + b1c);    // a1[col1], stays in register

        // L2: K-range [32kq,32kq+32), 2 cols/lane; a1 via readlane -> SGPR
        // (lane j holds a1[32kq+j] — wave-uniform index, no LDS).
        float A0 = 0.0f, A1 = 0.0f, B0 = 0.0f, B1 = 0.0f;
#pragma unroll
        for (int j = 0; j < 32; j += 2) {
            float s0 = readlane_f(a1v, j);
            float s1 = readlane_f(a1v, j + 1);
            A0 = fmaf(s0, w2a[j],     A0);
            B0 = fmaf(s0, w2b[j],     B0);
            A1 = fmaf(s1, w2a[j + 1], A1);
            B1 = fmaf(s1, w2b[j + 1], B1);
        }
        part[p][kq * 128 + c0] = A0 + A1;
        part[p][kq * 128 + c1] = B0 + B1;
        __syncthreads();                     // the ONE barrier per feval

        // combine (redundant per wave): 8 lane-consecutive ds_read_b32,
        // conflict-free; result into wave-private a2w.
        {
            float s0 = part[p][c0] + part[p][128 + c0]
                     + part[p][256 + c0] + part[p][384 + c0] + b2c0;
            float s1 = part[p][c1] + part[p][128 + c1]
                     + part[p][256 + c1] + part[p][384 + c1] + b2c1;
            a2w[kq][c0] = silu_f(s0);
            a2w[kq][c1] = silu_f(s1);
        }
        // intra-wave write->read: compiler inserts lgkmcnt

        // L3: output d, K-chunk g (32 wide), bank-staggered broadcast b128.
        v2f pp = {0.0f, 0.0f};
#pragma unroll
        for (int qq = 0; qq < 8; ++qq) {
            int qsel = (qq + 2 * g) & 7;
            float4 av = *(const float4*)&a2w[kq][32 * g + 4 * qsel];
            pp = fma2((v2f){ av.x, av.y }, w3r[2 * qq],     pp);
            pp = fma2((v2f){ av.z, av.w }, w3r[2 * qq + 1], pp);
        }
        // cross-group combine via wave-private LDS (one round trip)
        p3s[kq][lane] = pp.x + pp.y;
        float dz = b3d + p3s[kq][d] + p3s[kq][d + 16]
                       + p3s[kq][d + 32] + p3s[kq][d + 48];

        // One-pass LayerNorm: Σdz and Σdz² as independent DPP chains.
        float s1 = sum16_dpp(dz);
        float s2 = sum16_dpp(dz * dz);
        float m  = s1 * 0.0625f;
        float v  = fmaf(m, -m, s2 * 0.0625f);
        return (dz - m) * rsqrtf(v + 1e-5f) * lngd + lnbd;
    };

    for (int l = 0; l < 199; ++l) {
        const float dt = tvec[l + 1] - tvec[l];
        const float h  = dt * 0.125f;          // dt / K, K=8 (exact)
        const float zstart = z;
        for (int s = 0; s < 8; ++s) {
            // parities 0,1,0,1,0,1 (even count per substep => invariant)
            float k1 = feval(z, 0);
            float k2 = feval(z + h * (k1 * (float)(1.0 / 5.0)), 1);
            float k3 = feval(z + h * ((float)(3.0 / 40.0) * k1 + (float)(9.0 / 40.0) * k2), 0);
            float k4 = feval(z + h * ((float)(44.0 / 45.0) * k1 - (float)(56.0 / 15.0) * k2
                                    + (float)(32.0 / 9.0) * k3), 1);
            float k5 = feval(z + h * ((float)(19372.0 / 6561.0) * k1 - (float)(25360.0 / 2187.0) * k2
                                    + (float)(64448.0 / 6561.0) * k3 - (float)(212.0 / 729.0) * k4), 0);
            float k6 = feval(z + h * ((float)(9017.0 / 3168.0) * k1 - (float)(355.0 / 33.0) * k2
                                    + (float)(46732.0 / 5247.0) * k3 + (float)(49.0 / 176.0) * k4
                                    - (float)(5103.0 / 18656.0) * k5), 1);
            z = z + h * ((float)(35.0 / 384.0) * k1 + (float)(500.0 / 1113.0) * k3
                       + (float)(125.0 / 192.0) * k4 - (float)(2187.0 / 6784.0) * k5
                       + (float)(11.0 / 84.0) * k6);
        }
        if (tid < 16) {
            ztraj[(l + 1) * 16 + tid] = z;
            zdiff[l * 16 + tid] = (z - zstart) / dt;
        }
    }
}

// ---------------------------------------------------------------------------
// Decoder: fused 3-layer MLP over 51200 rows. M-tile=16, 256 threads,
// 4 blocks/CU to hide the L2-bound w2 reads. (unchanged)
// ---------------------------------------------------------------------------
#define GS 516   // padded LDS stride for the 16x512 activation tile

__global__ __launch_bounds__(256, 4) void dec_kernel(
    const float* __restrict__ ztr,
    const float* __restrict__ w1, const float* __restrict__ b1,
    const float* __restrict__ w2, const float* __restrict__ b2,
    const float* __restrict__ w3, const float* __restrict__ b3,
    float* __restrict__ xhat)
{
    __shared__ __align__(16) float zt[16 * 17];
    __shared__ __align__(16) float g[16 * GS];

    const int t    = threadIdx.x;
    const int blk  = blockIdx.x;
    const int tr   = t >> 5;
    const int tc   = t & 31;
    const int row0 = blk * 16;
    const int r0   = 2 * tr;

    {
        int r = t >> 4, dd = t & 15;
        zt[r * 17 + dd] = ztr[(row0 + r) * 16 + dd];
    }
    __syncthreads();

    // Phase A: g1 = relu(z @ w1 + b1), K=16
    {
        float acc[2][16];
#pragma unroll
        for (int p = 0; p < 2; ++p)
#pragma unroll
            for (int i = 0; i < 16; ++i) acc[p][i] = 0.0f;

#pragma unroll
        for (int k = 0; k < 16; ++k) {
            float a0 = zt[(r0 + 0) * 17 + k];
            float a1 = zt[(r0 + 1) * 17 + k];
            const float4* wr = (const float4*)(w1 + k * 512 + 16 * tc);
#pragma unroll
            for (int u = 0; u < 4; ++u) {
                float4 wv = wr[u];
                acc[0][4 * u + 0] = fmaf(a0, wv.x, acc[0][4 * u + 0]);
                acc[0][4 * u + 1] = fmaf(a0, wv.y, acc[0][4 * u + 1]);
                acc[0][4 * u + 2] = fmaf(a0, wv.z, acc[0][4 * u + 2]);
                acc[0][4 * u + 3] = fmaf(a0, wv.w, acc[0][4 * u + 3]);
                acc[1][4 * u + 0] = fmaf(a1, wv.x, acc[1][4 * u + 0]);
                acc[1][4 * u + 1] = fmaf(a1, wv.y, acc[1][4 * u + 1]);
                acc[1][4 * u + 2] = fmaf(a1, wv.z, acc[1][4 * u + 2]);
                acc[1][4 * u + 3] = fmaf(a1, wv.w, acc[1][4 * u + 3]);
            }
        }
        const float4* bb = (const float4*)(b1 + 16 * tc);
#pragma unroll
        for (int u = 0; u < 4; ++u) {
            float4 bv = bb[u];
#pragma unroll
            for (int p = 0; p < 2; ++p) {
                g[(r0 + p) * GS + 16 * tc + 4 * u + 0] = fmaxf(acc[p][4 * u + 0] + bv.x, 0.0f);
                g[(r0 + p) * GS + 16 * tc + 4 * u + 1] = fmaxf(acc[p][4 * u + 1] + bv.y, 0.0f);
                g[(r0 + p) * GS + 16 * tc + 4 * u + 2] = fmaxf(acc[p][4 * u + 2] + bv.z, 0.0f);
                g[(r0 + p) * GS + 16 * tc + 4 * u + 3] = fmaxf(acc[p][4 * u + 3] + bv.w, 0.0f);
            }
        }
    }
    __syncthreads();

    // Phase B: g2 = relu(g1 @ w2 + b2), K=512
    {
        float accB[2][16];
#pragma unroll
        for (int p = 0; p < 2; ++p)
#pragma unroll
            for (int i = 0; i < 16; ++i) accB[p][i] = 0.0f;

        for (int k4 = 0; k4 < 128; ++k4) {
            float4 av0 = *(const float4*)&g[(r0 + 0) * GS + 4 * k4];
            float4 av1 = *(const float4*)&g[(r0 + 1) * GS + 4 * k4];
            float a0[4] = {av0.x, av0.y, av0.z, av0.w};
            float a1[4] = {av1.x, av1.y, av1.z, av1.w};
#pragma unroll
            for (int u = 0; u < 4; ++u) {
                const float4* wr = (const float4*)(w2 + (4 * k4 + u) * 512 + 16 * tc);
#pragma unroll
                for (int q = 0; q < 4; ++q) {
                    float4 wv = wr[q];
                    accB[0][4 * q + 0] = fmaf(a0[u], wv.x, accB[0][4 * q + 0]);
                    accB[0][4 * q + 1] = fmaf(a0[u], wv.y, accB[0][4 * q + 1]);
                    accB[0][4 * q + 2] = fmaf(a0[u], wv.z, accB[0][4 * q + 2]);
                    accB[0][4 * q + 3] = fmaf(a0[u], wv.w, accB[0][4 * q + 3]);
                    accB[1][4 * q + 0] = fmaf(a1[u], wv.x, accB[1][4 * q + 0]);
                    accB[1][4 * q + 1] = fmaf(a1[u], wv.y, accB[1][4 * q + 1]);
                    accB[1][4 * q + 2] = fmaf(a1[u], wv.z, accB[1][4 * q + 2]);
                    accB[1][4 * q + 3] = fmaf(a1[u], wv.w, accB[1][4 * q + 3]);
                }
            }
        }
        __syncthreads();
        const float4* bb = (const float4*)(b2 + 16 * tc);
#pragma unroll
        for (int u = 0; u < 4; ++u) {
            float4 bv = bb[u];
#pragma unroll
            for (int p = 0; p < 2; ++p) {
                g[(r0 + p) * GS + 16 * tc + 4 * u + 0] = fmaxf(accB[p][4 * u + 0] + bv.x, 0.0f);
                g[(r0 + p) * GS + 16 * tc + 4 * u + 1] = fmaxf(accB[p][4 * u + 1] + bv.y, 0.0f);
                g[(r0 + p) * GS + 16 * tc + 4 * u + 2] = fmaxf(accB[p][4 * u + 2] + bv.z, 0.0f);
                g[(r0 + p) * GS + 16 * tc + 4 * u + 3] = fmaxf(accB[p][4 * u + 3] + bv.w, 0.0f);
            }
        }
    }
    __syncthreads();

    // Phase C: xhat = g2 @ w3 + b3, N=256 (8 cols/thread), K=512
    {
        float accC[2][8];
#pragma unroll
        for (int p = 0; p < 2; ++p)
#pragma unroll
            for (int i = 0; i < 8; ++i) accC[p][i] = 0.0f;

        for (int k4 = 0; k4 < 128; ++k4) {
            float4 av0 = *(const float4*)&g[(r0 + 0) * GS + 4 * k4];
            float4 av1 = *(const float4*)&g[(r0 + 1) * GS + 4 * k4];
            float a0[4] = {av0.x, av0.y, av0.z, av0.w};
            float a1[4] = {av1.x, av1.y, av1.z, av1.w};
#pragma unroll
            for (int u = 0; u < 4; ++u) {
                const float4* wr = (const float4*)(w3 + (4 * k4 + u) * 256 + 8 * tc);
                float4 w0 = wr[0], w1v = wr[1];
                accC[0][0] = fmaf(a0[u], w0.x,  accC[0][0]);
                accC[0][1] = fmaf(a0[u], w0.y,  accC[0][1]);
                accC[0][2] = fmaf(a0[u], w0.z,  accC[0][2]);
                accC[0][3] = fmaf(a0[u], w0.w,  accC[0][3]);
                accC[0][4] = fmaf(a0[u], w1v.x, accC[0][4]);
                accC[0][5] = fmaf(a0[u], w1v.y, accC[0][5]);
                accC[0][6] = fmaf(a0[u], w1v.z, accC[0][6]);
                accC[0][7] = fmaf(a0[u], w1v.w, accC[0][7]);
                accC[1][0] = fmaf(a1[u], w0.x,  accC[1][0]);
                accC[1][1] = fmaf(a1[u], w0.y,  accC[1][1]);
                accC[1][2] = fmaf(a1[u], w0.z,  accC[1][2]);
                accC[1][3] = fmaf(a1[u], w0.w,  accC[1][3]);
                accC[1][4] = fmaf(a1[u], w1v.x, accC[1][4]);
                accC[1][5] = fmaf(a1[u], w1v.y, accC[1][5]);
                accC[1][6] = fmaf(a1[u], w1v.z, accC[1][6]);
                accC[1][7] = fmaf(a1[u], w1v.w, accC[1][7]);
            }
        }
        const float4* bb = (const float4*)(b3 + 8 * tc);
        float4 bv0 = bb[0], bv1 = bb[1];
#pragma unroll
        for (int p = 0; p < 2; ++p) {
            float4 o0 = make_float4(accC[p][0] + bv0.x, accC[p][1] + bv0.y,
                                    accC[p][2] + bv0.z, accC[p][3] + bv0.w);
            float4 o1 = make_float4(accC[p][4] + bv1.x, accC[p][5] + bv1.y,
                                    accC[p][6] + bv1.z, accC[p][7] + bv1.w);
            float* dst = xhat + (size_t)(row0 + r0 + p) * 256 + 8 * tc;
            *(float4*)(dst)     = o0;
            *(float4*)(dst + 4) = o1;
        }
    }
}

extern "C" void kernel_launch(void* const* d_in, const int* in_sizes, int n_in,
                              void* d_out, int out_size, void* d_ws, size_t ws_size,
                              hipStream_t stream) {
    const float* x_seq  = (const float*)d_in[0];
    const float* tvec   = (const float*)d_in[1];
    const float* eps    = (const float*)d_in[2];
    const float* enc_w1 = (const float*)d_in[3];
    const float* enc_b1 = (const float*)d_in[4];
    const float* enc_w2 = (const float*)d_in[5];
    const float* enc_b2 = (const float*)d_in[6];
    const float* enc_w3 = (const float*)d_in[7];
    const float* enc_b3 = (const float*)d_in[8];
    const float* mu_w   = (const float*)d_in[9];
    const float* mu_b   = (const float*)d_in[10];
    const float* lv_w   = (const float*)d_in[11];
    const float* lv_b   = (const float*)d_in[12];
    const float* ode_w1 = (const float*)d_in[13];
    const float* ode_b1 = (const float*)d_in[14];
    const float* ode_w2 = (const float*)d_in[15];
    const float* ode_b2 = (const float*)d_in[16];
    const float* ode_w3 = (const float*)d_in[17];
    const float* ode_b3 = (const float*)d_in[18];
    const float* ln_g   = (const float*)d_in[19];
    const float* ln_b   = (const float*)d_in[20];
    const float* dec_w1 = (const float*)d_in[21];
    const float* dec_b1 = (const float*)d_in[22];
    const float* dec_w2 = (const float*)d_in[23];
    const float* dec_b2 = (const float*)d_in[24];
    const float* dec_w3 = (const float*)d_in[25];
    const float* dec_b3 = (const float*)d_in[26];
    float* out = (float*)d_out;

    enc_kernel<<<256, 256, 0, stream>>>(x_seq, eps, enc_w1, enc_b1, enc_w2, enc_b2,
                                        enc_w3, enc_b3, mu_w, mu_b, lv_w, lv_b, out);
    ode_kernel<<<256, 256, 0, stream>>>(tvec, ode_w1, ode_b1, ode_w2, ode_b2,
                                        ode_w3, ode_b3, ln_g, ln_b, out);
    dec_kernel<<<3200, 256, 0, stream>>>(out + OFF_ZT, dec_w1, dec_b1, dec_w2, dec_b2,
                                         dec_w3, dec_b3, out);
}

// Round 12
// 8982.700 us; speedup vs baseline: 1.4102x; 1.0139x over previous
//
#include <hip/hip_runtime.h>

// Output layout (flat f32, reference return order):
//   xhat  : B*L*N   = 13,107,200  @ 0
//   mu    : B*D     =      4,096  @ 13,107,200
//   logvar: B*D     =      4,096  @ 13,111,296
//   z_traj: B*L*D   =    819,200  @ 13,115,392
//   zdiff : B*(L-1)*D =  815,104  @ 13,934,592
#define OFF_MU   13107200
#define OFF_LV   13111296
#define OFF_ZT   13115392
#define OFF_ZD   13934592

typedef float v2f __attribute__((ext_vector_type(2)));

__device__ __forceinline__ float silu_f(float x) {
    return x / (1.0f + __expf(-x));
}

__device__ __forceinline__ float readlane_f(float v, int l) {
    return __uint_as_float(__builtin_amdgcn_readlane(__float_as_uint(v), l));
}

__device__ __forceinline__ v2f fma2(v2f a, v2f b, v2f c) {
    return __builtin_elementwise_fma(a, b, c);
}

// x + dpp_move(x) with compile-time DPP control. VALU-latency cross-lane.
template <int CTRL>
__device__ __forceinline__ float dppadd(float x) {
    int y = __builtin_amdgcn_update_dpp(0, __float_as_int(x), CTRL, 0xF, 0xF, true);
    return x + __int_as_float(y);
}

// Sum of x over each 16-lane row (values replicated per row afterwards).
__device__ __forceinline__ float sum16_dpp(float x) {
    x = dppadd<0xB1>(x);    // quad_perm xor1
    x = dppadd<0x4E>(x);    // quad_perm xor2
    x = dppadd<0x141>(x);   // row_half_mirror (xor4 once quad-uniform)
    x = dppadd<0x140>(x);   // row_mirror (xor8 once 8-uniform)
    return x;
}

// ---------------------------------------------------------------------------
// Encoder: one block per batch row. x0(256) -> 512 -> 256 -> 128 -> mu/lv(16)
// (unchanged — negligible cost)
// ---------------------------------------------------------------------------
__global__ __launch_bounds__(256) void enc_kernel(
    const float* __restrict__ xseq, const float* __restrict__ eps,
    const float* __restrict__ w1, const float* __restrict__ b1,
    const float* __restrict__ w2, const float* __restrict__ b2,
    const float* __restrict__ w3, const float* __restrict__ b3,
    const float* __restrict__ muw, const float* __restrict__ mub,
    const float* __restrict__ lvw, const float* __restrict__ lvb,
    float* __restrict__ out)
{
    __shared__ float xr[256];
    __shared__ float h1[512];
    __shared__ float h2[256];
    __shared__ float h3[128];

    const int t = threadIdx.x;
    const int b = blockIdx.x;

    xr[t] = xseq[b * (200 * 256) + t];
    __syncthreads();

    {
        float acc0 = b1[t], acc1 = b1[t + 256];
        for (int i = 0; i < 256; ++i) {
            float xv = xr[i];
            acc0 = fmaf(xv, w1[i * 512 + t],       acc0);
            acc1 = fmaf(xv, w1[i * 512 + t + 256], acc1);
        }
        h1[t]       = fmaxf(acc0, 0.0f);
        h1[t + 256] = fmaxf(acc1, 0.0f);
    }
    __syncthreads();

    {
        float acc = b2[t];
        for (int i = 0; i < 512; ++i) acc = fmaf(h1[i], w2[i * 256 + t], acc);
        h2[t] = fmaxf(acc, 0.0f);
    }
    __syncthreads();

    if (t < 128) {
        float acc = b3[t];
        for (int i = 0; i < 256; ++i) acc = fmaf(h2[i], w3[i * 128 + t], acc);
        h3[t] = fmaxf(acc, 0.0f);
    }
    __syncthreads();

    if (t < 16) {
        float mu = mub[t], lv = lvb[t];
        for (int i = 0; i < 128; ++i) {
            float hv = h3[i];
            mu = fmaf(hv, muw[i * 16 + t], mu);
            lv = fmaf(hv, lvw[i * 16 + t], lv);
        }
        out[OFF_MU + b * 16 + t] = mu;
        out[OFF_LV + b * 16 + t] = lv;
        float z0 = mu + __expf(0.5f * lv) * eps[b * 16 + t];
        out[OFF_ZT + b * 3200 + t] = z0;
    }
}

// ---------------------------------------------------------------------------
// ODE integrator v12: v8's low-ISSUE datapath + v11's low-LATENCY sync.
//   From v8 (proven): 4 waves K-split-4; a1 in wave-private LDS (lanes<32
//   write, broadcast ds_read_b128 + pk-FMA in L2) — 578 issue-cyc/feval.
//   From v11 (proven): ONE barrier/feval via parity-double-buffered `part`
//   + redundant per-wave combine into wave-private a2w.
//   R11 lesson: readlane-L2 traded latency for issue 1:1 (VALU 32->53%,
//   net wash). This version takes only the sync win.
//   Race audit: a1s/a2w/p3s wave-private (lgkmcnt ordering). part[p]:
//   readers of feval N (after barrier N) precede barrier N+1; next writer
//   of part[p] is feval N+2's L2, after barrier N+1 — safe.
// ---------------------------------------------------------------------------
__global__ __launch_bounds__(256, 1) void ode_kernel(
    const float* __restrict__ tvec,
    const float* __restrict__ ow1, const float* __restrict__ ob1,
    const float* __restrict__ ow2, const float* __restrict__ ob2,
    const float* __restrict__ ow3, const float* __restrict__ ob3,
    const float* __restrict__ lng, const float* __restrict__ lnb,
    float* __restrict__ out)
{
    __shared__ __align__(16) float a1s[4][32];        // wave-private a1 slices
    __shared__ __align__(16) float part[2][4 * 128];  // [parity][kq*128+col]
    __shared__ __align__(16) float a2w[4][128];       // wave-private combine
    __shared__ __align__(16) float p3s[4][64];        // wave-private L3 partials

    const int tid  = threadIdx.x;
    const int kq   = tid >> 6;       // wave id 0..3 = K-quarter
    const int lane = tid & 63;
    const int b    = blockIdx.x;
    const int d    = lane & 15;      // owned z-dim (replicated x4 per wave)
    const int g    = lane >> 4;      // L3 K-chunk group
    const int c0   = lane, c1 = lane + 64;      // L2 output columns
    const int col1 = 32 * kq + (lane & 31);     // L1 column (lanes<32 write)

    // ---- register-resident weights via volatile (loaded exactly once) -----
    const volatile float* vw1 = ow1;
    const volatile float* vw2 = ow2;
    const volatile float* vw3 = ow3;

    float w1r[16];
#pragma unroll
    for (int k = 0; k < 16; ++k) w1r[k] = vw1[k * 128 + col1];

    v2f w2r0[16], w2r1[16];          // K-quarter kq, cols c0/c1, K-pairs
#pragma unroll
    for (int q = 0; q < 16; ++q) {
        int k0 = 32 * kq + 2 * q;
        v2f t0 = { vw2[k0 * 128 + c0], vw2[(k0 + 1) * 128 + c0] };
        v2f t1 = { vw2[k0 * 128 + c1], vw2[(k0 + 1) * 128 + c1] };
        w2r0[q] = t0;
        w2r1[q] = t1;
    }
    v2f w3r[16];   // K-chunk g (32 wide), stored in bank-staggered read order
#pragma unroll
    for (int qq = 0; qq < 8; ++qq) {
        int qsel = (qq + 2 * g) & 7;
        int k0   = 32 * g + 4 * qsel;
        v2f t0 = { vw3[(k0 + 0) * 16 + d], vw3[(k0 + 1) * 16 + d] };
        v2f t1 = { vw3[(k0 + 2) * 16 + d], vw3[(k0 + 3) * 16 + d] };
        w3r[2 * qq]     = t0;
        w3r[2 * qq + 1] = t1;
    }
    const volatile float* vb1 = ob1;
    const volatile float* vb2 = ob2;
    const volatile float* vb3 = ob3;
    const volatile float* vlg = lng;
    const volatile float* vlb = lnb;
    const float b1c  = vb1[col1];
    const float b2c0 = vb2[c0], b2c1 = vb2[c1];
    const float b3d  = vb3[d];
    const float lngd = vlg[d], lnbd = vlb[d];

    float* ztraj = out + OFF_ZT + b * 3200;   // [200][16]
    float* zdiff = out + OFF_ZD + b * 3184;   // [199][16]

    float z = ztraj[d];                       // z0, replicated, all waves

    // one evaluation of f(za); za = zarg[d] per lane (replicated x4).
    // p = compile-time parity selecting the part buffer.
    auto feval = [&](float za, int p) -> float {
        // L1: this wave's 32 a1 columns. zarg via readlane -> SGPR.
        float ae = 0.0f, ao = 0.0f;
#pragma unroll
        for (int k = 0; k < 16; k += 2) {
            float zk0 = readlane_f(za, k);
            float zk1 = readlane_f(za, k + 1);
            ae = fmaf(zk0, w1r[k],     ae);
            ao = fmaf(zk1, w1r[k + 1], ao);
        }
        if (lane < 32) a1s[kq][lane] = silu_f(ae + ao + b1c);
        // intra-wave write->read: compiler inserts lgkmcnt, no barrier

        // L2 partial: K-range [32kq,32kq+32), 2 cols/lane.
        // a1 via 8 broadcast b128 reads; weights pure registers (pk-FMA).
        v2f A  = {0.0f, 0.0f}, Ab = {0.0f, 0.0f};
        v2f B  = {0.0f, 0.0f}, Bb = {0.0f, 0.0f};
        const float4* a14 = (const float4*)a1s[kq];
#pragma unroll
        for (int i = 0; i < 8; ++i) {
            float4 av = a14[i];
            v2f plo = { av.x, av.y };
            v2f phi = { av.z, av.w };
            A  = fma2(plo, w2r0[2 * i],     A);
            Ab = fma2(phi, w2r0[2 * i + 1], Ab);
            B  = fma2(plo, w2r1[2 * i],     B);
            Bb = fma2(phi, w2r1[2 * i + 1], Bb);
        }
        part[p][kq * 128 + c0] = A.x + A.y + Ab.x + Ab.y;
        part[p][kq * 128 + c1] = B.x + B.y + Bb.x + Bb.y;
        __syncthreads();                     // the ONE barrier per feval

        // combine (redundant per wave): 8 lane-consecutive ds_read_b32,
        // conflict-free; result into wave-private a2w.
        {
            float s0 = part[p][c0] + part[p][128 + c0]
                     + part[p][256 + c0] + part[p][384 + c0] + b2c0;
            float s1 = part[p][c1] + part[p][128 + c1]
                     + part[p][256 + c1] + part[p][384 + c1] + b2c1;
            a2w[kq][c0] = silu_f(s0);
            a2w[kq][c1] = silu_f(s1);
        }
        // intra-wave write->read: compiler inserts lgkmcnt

        // L3: output d, K-chunk g (32 wide), bank-staggered broadcast b128.
        v2f pp = {0.0f, 0.0f};
#pragma unroll
        for (int qq = 0; qq < 8; ++qq) {
            int qsel = (qq + 2 * g) & 7;
            float4 av = *(const float4*)&a2w[kq][32 * g + 4 * qsel];
            pp = fma2((v2f){ av.x, av.y }, w3r[2 * qq],     pp);
            pp = fma2((v2f){ av.z, av.w }, w3r[2 * qq + 1], pp);
        }
        // cross-group combine via wave-private LDS (one round trip)
        p3s[kq][lane] = pp.x + pp.y;
        float dz = b3d + p3s[kq][d] + p3s[kq][d + 16]
                       + p3s[kq][d + 32] + p3s[kq][d + 48];

        // One-pass LayerNorm: Σdz and Σdz² as independent DPP chains.
        float s1 = sum16_dpp(dz);
        float s2 = sum16_dpp(dz * dz);
        float m  = s1 * 0.0625f;
        float v  = fmaf(m, -m, s2 * 0.0625f);
        return (dz - m) * rsqrtf(v + 1e-5f) * lngd + lnbd;
    };

    for (int l = 0; l < 199; ++l) {
        const float dt = tvec[l + 1] - tvec[l];
        const float h  = dt * 0.125f;          // dt / K, K=8 (exact)
        const float zstart = z;
        for (int s = 0; s < 8; ++s) {
            // parities 0,1,0,1,0,1 (even count per substep => invariant)
            float k1 = feval(z, 0);
            float k2 = feval(z + h * (k1 * (float)(1.0 / 5.0)), 1);
            float k3 = feval(z + h * ((float)(3.0 / 40.0) * k1 + (float)(9.0 / 40.0) * k2), 0);
            float k4 = feval(z + h * ((float)(44.0 / 45.0) * k1 - (float)(56.0 / 15.0) * k2
                                    + (float)(32.0 / 9.0) * k3), 1);
            float k5 = feval(z + h * ((float)(19372.0 / 6561.0) * k1 - (float)(25360.0 / 2187.0) * k2
                                    + (float)(64448.0 / 6561.0) * k3 - (float)(212.0 / 729.0) * k4), 0);
            float k6 = feval(z + h * ((float)(9017.0 / 3168.0) * k1 - (float)(355.0 / 33.0) * k2
                                    + (float)(46732.0 / 5247.0) * k3 + (float)(49.0 / 176.0) * k4
                                    - (float)(5103.0 / 18656.0) * k5), 1);
            z = z + h * ((float)(35.0 / 384.0) * k1 + (float)(500.0 / 1113.0) * k3
                       + (float)(125.0 / 192.0) * k4 - (float)(2187.0 / 6784.0) * k5
                       + (float)(11.0 / 84.0) * k6);
        }
        if (tid < 16) {
            ztraj[(l + 1) * 16 + tid] = z;
            zdiff[l * 16 + tid] = (z - zstart) / dt;
        }
    }
}

// ---------------------------------------------------------------------------
// Decoder: fused 3-layer MLP over 51200 rows. M-tile=16, 256 threads,
// 4 blocks/CU to hide the L2-bound w2 reads. (unchanged)
// ---------------------------------------------------------------------------
#define GS 516   // padded LDS stride for the 16x512 activation tile

__global__ __launch_bounds__(256, 4) void dec_kernel(
    const float* __restrict__ ztr,
    const float* __restrict__ w1, const float* __restrict__ b1,
    const float* __restrict__ w2, const float* __restrict__ b2,
    const float* __restrict__ w3, const float* __restrict__ b3,
    float* __restrict__ xhat)
{
    __shared__ __align__(16) float zt[16 * 17];
    __shared__ __align__(16) float g[16 * GS];

    const int t    = threadIdx.x;
    const int blk  = blockIdx.x;
    const int tr   = t >> 5;
    const int tc   = t & 31;
    const int row0 = blk * 16;
    const int r0   = 2 * tr;

    {
        int r = t >> 4, dd = t & 15;
        zt[r * 17 + dd] = ztr[(row0 + r) * 16 + dd];
    }
    __syncthreads();

    // Phase A: g1 = relu(z @ w1 + b1), K=16
    {
        float acc[2][16];
#pragma unroll
        for (int p = 0; p < 2; ++p)
#pragma unroll
            for (int i = 0; i < 16; ++i) acc[p][i] = 0.0f;

#pragma unroll
        for (int k = 0; k < 16; ++k) {
            float a0 = zt[(r0 + 0) * 17 + k];
            float a1 = zt[(r0 + 1) * 17 + k];
            const float4* wr = (const float4*)(w1 + k * 512 + 16 * tc);
#pragma unroll
            for (int u = 0; u < 4; ++u) {
                float4 wv = wr[u];
                acc[0][4 * u + 0] = fmaf(a0, wv.x, acc[0][4 * u + 0]);
                acc[0][4 * u + 1] = fmaf(a0, wv.y, acc[0][4 * u + 1]);
                acc[0][4 * u + 2] = fmaf(a0, wv.z, acc[0][4 * u + 2]);
                acc[0][4 * u + 3] = fmaf(a0, wv.w, acc[0][4 * u + 3]);
                acc[1][4 * u + 0] = fmaf(a1, wv.x, acc[1][4 * u + 0]);
                acc[1][4 * u + 1] = fmaf(a1, wv.y, acc[1][4 * u + 1]);
                acc[1][4 * u + 2] = fmaf(a1, wv.z, acc[1][4 * u + 2]);
                acc[1][4 * u + 3] = fmaf(a1, wv.w, acc[1][4 * u + 3]);
            }
        }
        const float4* bb = (const float4*)(b1 + 16 * tc);
#pragma unroll
        for (int u = 0; u < 4; ++u) {
            float4 bv = bb[u];
#pragma unroll
            for (int p = 0; p < 2; ++p) {
                g[(r0 + p) * GS + 16 * tc + 4 * u + 0] = fmaxf(acc[p][4 * u + 0] + bv.x, 0.0f);
                g[(r0 + p) * GS + 16 * tc + 4 * u + 1] = fmaxf(acc[p][4 * u + 1] + bv.y, 0.0f);
                g[(r0 + p) * GS + 16 * tc + 4 * u + 2] = fmaxf(acc[p][4 * u + 2] + bv.z, 0.0f);
                g[(r0 + p) * GS + 16 * tc + 4 * u + 3] = fmaxf(acc[p][4 * u + 3] + bv.w, 0.0f);
            }
        }
    }
    __syncthreads();

    // Phase B: g2 = relu(g1 @ w2 + b2), K=512
    {
        float accB[2][16];
#pragma unroll
        for (int p = 0; p < 2; ++p)
#pragma unroll
            for (int i = 0; i < 16; ++i) accB[p][i] = 0.0f;

        for (int k4 = 0; k4 < 128; ++k4) {
            float4 av0 = *(const float4*)&g[(r0 + 0) * GS + 4 * k4];
            float4 av1 = *(const float4*)&g[(r0 + 1) * GS + 4 * k4];
            float a0[4] = {av0.x, av0.y, av0.z, av0.w};
            float a1[4] = {av1.x, av1.y, av1.z, av1.w};
#pragma unroll
            for (int u = 0; u < 4; ++u) {
                const float4* wr = (const float4*)(w2 + (4 * k4 + u) * 512 + 16 * tc);
#pragma unroll
                for (int q = 0; q < 4; ++q) {
                    float4 wv = wr[q];
                    accB[0][4 * q + 0] = fmaf(a0[u], wv.x, accB[0][4 * q + 0]);
                    accB[0][4 * q + 1] = fmaf(a0[u], wv.y, accB[0][4 * q + 1]);
                    accB[0][4 * q + 2] = fmaf(a0[u], wv.z, accB[0][4 * q + 2]);
                    accB[0][4 * q + 3] = fmaf(a0[u], wv.w, accB[0][4 * q + 3]);
                    accB[1][4 * q + 0] = fmaf(a1[u], wv.x, accB[1][4 * q + 0]);
                    accB[1][4 * q + 1] = fmaf(a1[u], wv.y, accB[1][4 * q + 1]);
                    accB[1][4 * q + 2] = fmaf(a1[u], wv.z, accB[1][4 * q + 2]);
                    accB[1][4 * q + 3] = fmaf(a1[u], wv.w, accB[1][4 * q + 3]);
                }
            }
        }
        __syncthreads();
        const float4* bb = (const float4*)(b2 + 16 * tc);
#pragma unroll
        for (int u = 0; u < 4; ++u) {
            float4 bv = bb[u];
#pragma unroll
            for (int p = 0; p < 2; ++p) {
                g[(r0 + p) * GS + 16 * tc + 4 * u + 0] = fmaxf(accB[p][4 * u + 0] + bv.x, 0.0f);
                g[(r0 + p) * GS + 16 * tc + 4 * u + 1] = fmaxf(accB[p][4 * u + 1] + bv.y, 0.0f);
                g[(r0 + p) * GS + 16 * tc + 4 * u + 2] = fmaxf(accB[p][4 * u + 2] + bv.z, 0.0f);
                g[(r0 + p) * GS + 16 * tc + 4 * u + 3] = fmaxf(accB[p][4 * u + 3] + bv.w, 0.0f);
            }
        }
    }
    __syncthreads();

    // Phase C: xhat = g2 @ w3 + b3, N=256 (8 cols/thread), K=512
    {
        float accC[2][8];
#pragma unroll
        for (int p = 0; p < 2; ++p)
#pragma unroll
            for (int i = 0; i < 8; ++i) accC[p][i] = 0.0f;

        for (int k4 = 0; k4 < 128; ++k4) {
            float4 av0 = *(const float4*)&g[(r0 + 0) * GS + 4 * k4];
            float4 av1 = *(const float4*)&g[(r0 + 1) * GS + 4 * k4];
            float a0[4] = {av0.x, av0.y, av0.z, av0.w};
            float a1[4] = {av1.x, av1.y, av1.z, av1.w};
#pragma unroll
            for (int u = 0; u < 4; ++u) {
                const float4* wr = (const float4*)(w3 + (4 * k4 + u) * 256 + 8 * tc);
                float4 w0 = wr[0], w1v = wr[1];
                accC[0][0] = fmaf(a0[u], w0.x,  accC[0][0]);
                accC[0][1] = fmaf(a0[u], w0.y,  accC[0][1]);
                accC[0][2] = fmaf(a0[u], w0.z,  accC[0][2]);
                accC[0][3] = fmaf(a0[u], w0.w,  accC[0][3]);
                accC[0][4] = fmaf(a0[u], w1v.x, accC[0][4]);
                accC[0][5] = fmaf(a0[u], w1v.y, accC[0][5]);
                accC[0][6] = fmaf(a0[u], w1v.z, accC[0][6]);
                accC[0][7] = fmaf(a0[u], w1v.w, accC[0][7]);
                accC[1][0] = fmaf(a1[u], w0.x,  accC[1][0]);
                accC[1][1] = fmaf(a1[u], w0.y,  accC[1][1]);
                accC[1][2] = fmaf(a1[u], w0.z,  accC[1][2]);
                accC[1][3] = fmaf(a1[u], w0.w,  accC[1][3]);
                accC[1][4] = fmaf(a1[u], w1v.x, accC[1][4]);
                accC[1][5] = fmaf(a1[u], w1v.y, accC[1][5]);
                accC[1][6] = fmaf(a1[u], w1v.z, accC[1][6]);
                accC[1][7] = fmaf(a1[u], w1v.w, accC[1][7]);
            }
        }
        const float4* bb = (const float4*)(b3 + 8 * tc);
        float4 bv0 = bb[0], bv1 = bb[1];
#pragma unroll
        for (int p = 0; p < 2; ++p) {
            float4 o0 = make_float4(accC[p][0] + bv0.x, accC[p][1] + bv0.y,
                                    accC[p][2] + bv0.z, accC[p][3] + bv0.w);
            float4 o1 = make_float4(accC[p][4] + bv1.x, accC[p][5] + bv1.y,
                                    accC[p][6] + bv1.z, accC[p][7] + bv1.w);
            float* dst = xhat + (size_t)(row0 + r0 + p) * 256 + 8 * tc;
            *(float4*)(dst)     = o0;
            *(float4*)(dst + 4) = o1;
        }
    }
}

extern "C" void kernel_launch(void* const* d_in, const int* in_sizes, int n_in,
                              void* d_out, int out_size, void* d_ws, size_t ws_size,
                              hipStream_t stream) {
    const float* x_seq  = (const float*)d_in[0];
    const float* tvec   = (const float*)d_in[1];
    const float* eps    = (const float*)d_in[2];
    const float* enc_w1 = (const float*)d_in[3];
    const float* enc_b1 = (const float*)d_in[4];
    const float* enc_w2 = (const float*)d_in[5];
    const float* enc_b2 = (const float*)d_in[6];
    const float* enc_w3 = (const float*)d_in[7];
    const float* enc_b3 = (const float*)d_in[8];
    const float* mu_w   = (const float*)d_in[9];
    const float* mu_b   = (const float*)d_in[10];
    const float* lv_w   = (const float*)d_in[11];
    const float* lv_b   = (const float*)d_in[12];
    const float* ode_w1 = (const float*)d_in[13];
    const float* ode_b1 = (const float*)d_in[14];
    const float* ode_w2 = (const float*)d_in[15];
    const float* ode_b2 = (const float*)d_in[16];
    const float* ode_w3 = (const float*)d_in[17];
    const float* ode_b3 = (const float*)d_in[18];
    const float* ln_g   = (const float*)d_in[19];
    const float* ln_b   = (const float*)d_in[20];
    const float* dec_w1 = (const float*)d_in[21];
    const float* dec_b1 = (const float*)d_in[22];
    const float* dec_w2 = (const float*)d_in[23];
    const float* dec_b2 = (const float*)d_in[24];
    const float* dec_w3 = (const float*)d_in[25];
    const float* dec_b3 = (const float*)d_in[26];
    float* out = (float*)d_out;

    enc_kernel<<<256, 256, 0, stream>>>(x_seq, eps, enc_w1, enc_b1, enc_w2, enc_b2,
                                        enc_w3, enc_b3, mu_w, mu_b, lv_w, lv_b, out);
    ode_kernel<<<256, 256, 0, stream>>>(tvec, ode_w1, ode_b1, ode_w2, ode_b2,
                                        ode_w3, ode_b3, ln_g, ln_b, out);
    dec_kernel<<<3200, 256, 0, stream>>>(out + OFF_ZT, dec_w1, dec_b1, dec_w2, dec_b2,
                                         dec_w3, dec_b3, out);
}

// Round 13
// 8087.155 us; speedup vs baseline: 1.5664x; 1.1107x over previous
//
#include <hip/hip_runtime.h>

// Output layout (flat f32, reference return order):
//   xhat  : B*L*N   = 13,107,200  @ 0
//   mu    : B*D     =      4,096  @ 13,107,200
//   logvar: B*D     =      4,096  @ 13,111,296
//   z_traj: B*L*D   =    819,200  @ 13,115,392
//   zdiff : B*(L-1)*D =  815,104  @ 13,934,592
#define OFF_MU   13107200
#define OFF_LV   13111296
#define OFF_ZT   13115392
#define OFF_ZD   13934592

typedef float v2f __attribute__((ext_vector_type(2)));

__device__ __forceinline__ float silu_f(float x) {
    return x / (1.0f + __expf(-x));
}

__device__ __forceinline__ float readlane_f(float v, int l) {
    return __uint_as_float(__builtin_amdgcn_readlane(__float_as_uint(v), l));
}

__device__ __forceinline__ v2f fma2(v2f a, v2f b, v2f c) {
    return __builtin_elementwise_fma(a, b, c);
}

// x + dpp_move(x) with compile-time DPP control. VALU-latency cross-lane.
template <int CTRL>
__device__ __forceinline__ float dppadd(float x) {
    int y = __builtin_amdgcn_update_dpp(0, __float_as_int(x), CTRL, 0xF, 0xF, true);
    return x + __int_as_float(y);
}

// Sum of x over each 16-lane row (values replicated per row afterwards).
__device__ __forceinline__ float sum16_dpp(float x) {
    x = dppadd<0xB1>(x);    // quad_perm xor1
    x = dppadd<0x4E>(x);    // quad_perm xor2
    x = dppadd<0x141>(x);   // row_half_mirror (xor4 once quad-uniform)
    x = dppadd<0x140>(x);   // row_mirror (xor8 once 8-uniform)
    return x;
}

// ---------------------------------------------------------------------------
// Encoder: one block per batch row. x0(256) -> 512 -> 256 -> 128 -> mu/lv(16)
// (unchanged — negligible cost)
// ---------------------------------------------------------------------------
__global__ __launch_bounds__(256) void enc_kernel(
    const float* __restrict__ xseq, const float* __restrict__ eps,
    const float* __restrict__ w1, const float* __restrict__ b1,
    const float* __restrict__ w2, const float* __restrict__ b2,
    const float* __restrict__ w3, const float* __restrict__ b3,
    const float* __restrict__ muw, const float* __restrict__ mub,
    const float* __restrict__ lvw, const float* __restrict__ lvb,
    float* __restrict__ out)
{
    __shared__ float xr[256];
    __shared__ float h1[512];
    __shared__ float h2[256];
    __shared__ float h3[128];

    const int t = threadIdx.x;
    const int b = blockIdx.x;

    xr[t] = xseq[b * (200 * 256) + t];
    __syncthreads();

    {
        float acc0 = b1[t], acc1 = b1[t + 256];
        for (int i = 0; i < 256; ++i) {
            float xv = xr[i];
            acc0 = fmaf(xv, w1[i * 512 + t],       acc0);
            acc1 = fmaf(xv, w1[i * 512 + t + 256], acc1);
        }
        h1[t]       = fmaxf(acc0, 0.0f);
        h1[t + 256] = fmaxf(acc1, 0.0f);
    }
    __syncthreads();

    {
        float acc = b2[t];
        for (int i = 0; i < 512; ++i) acc = fmaf(h1[i], w2[i * 256 + t], acc);
        h2[t] = fmaxf(acc, 0.0f);
    }
    __syncthreads();

    if (t < 128) {
        float acc = b3[t];
        for (int i = 0; i < 256; ++i) acc = fmaf(h2[i], w3[i * 128 + t], acc);
        h3[t] = fmaxf(acc, 0.0f);
    }
    __syncthreads();

    if (t < 16) {
        float mu = mub[t], lv = lvb[t];
        for (int i = 0; i < 128; ++i) {
            float hv = h3[i];
            mu = fmaf(hv, muw[i * 16 + t], mu);
            lv = fmaf(hv, lvw[i * 16 + t], lv);
        }
        out[OFF_MU + b * 16 + t] = mu;
        out[OFF_LV + b * 16 + t] = lv;
        float z0 = mu + __expf(0.5f * lv) * eps[b * 16 + t];
        out[OFF_ZT + b * 3200 + t] = z0;
    }
}

// ---------------------------------------------------------------------------
// ODE integrator v8 (EXACT revert — best measured: 7191 us, 1807 cyc/feval).
//   4 waves K-split-4, per-lane weights 112 floats (under the ~132 VGPR cap),
//   wave-private a1s, two barriers (part -> combine by threads<128 -> a2s),
//   wave-private p3s L3 combine, one-pass DPP LayerNorm.
//   R11/R12 lesson: single-barrier variants trade issue for latency 1:1 —
//   this two-barrier split-combine is the measured minimum.
// ---------------------------------------------------------------------------
__global__ __launch_bounds__(256, 1) void ode_kernel(
    const float* __restrict__ tvec,
    const float* __restrict__ ow1, const float* __restrict__ ob1,
    const float* __restrict__ ow2, const float* __restrict__ ob2,
    const float* __restrict__ ow3, const float* __restrict__ ob3,
    const float* __restrict__ lng, const float* __restrict__ lnb,
    float* __restrict__ out)
{
    __shared__ __align__(16) float a1s[4][32];    // wave-private a1 slices
    __shared__ __align__(16) float part[4 * 128]; // L2 partials [wave][col]
    __shared__ __align__(16) float a2s[128];
    __shared__ __align__(16) float p3s[4 * 64];   // wave-private L3 partials

    const int tid  = threadIdx.x;
    const int wv   = tid >> 6;       // wave id 0..3 = K-quarter
    const int lane = tid & 63;
    const int b    = blockIdx.x;
    const int d    = lane & 15;      // owned z-dim (replicated x4 per wave)
    const int g    = lane >> 4;      // L3 K-chunk group
    const int c0   = lane, c1 = lane + 64;      // L2 output columns
    const int col1 = 32 * wv + (lane & 31);     // L1 column (lanes<32 write)

    // ---- register-resident weights via volatile (loaded exactly once) -----
    const volatile float* vw1 = ow1;
    const volatile float* vw2 = ow2;
    const volatile float* vw3 = ow3;

    float w1r[16];
#pragma unroll
    for (int k = 0; k < 16; ++k) w1r[k] = vw1[k * 128 + col1];

    v2f w2r0[16], w2r1[16];          // K-quarter wv, cols c0/c1, K-pairs
#pragma unroll
    for (int q = 0; q < 16; ++q) {
        int k0 = 32 * wv + 2 * q;
        v2f t0 = { vw2[k0 * 128 + c0], vw2[(k0 + 1) * 128 + c0] };
        v2f t1 = { vw2[k0 * 128 + c1], vw2[(k0 + 1) * 128 + c1] };
        w2r0[q] = t0;
        w2r1[q] = t1;
    }
    v2f w3r[16];   // K-chunk g (32 wide), stored in bank-staggered read order
#pragma unroll
    for (int qq = 0; qq < 8; ++qq) {
        int qsel = (qq + 2 * g) & 7;
        int k0   = 32 * g + 4 * qsel;
        v2f t0 = { vw3[(k0 + 0) * 16 + d], vw3[(k0 + 1) * 16 + d] };
        v2f t1 = { vw3[(k0 + 2) * 16 + d], vw3[(k0 + 3) * 16 + d] };
        w3r[2 * qq]     = t0;
        w3r[2 * qq + 1] = t1;
    }
    const volatile float* vb1 = ob1;
    const volatile float* vb2 = ob2;
    const volatile float* vb3 = ob3;
    const volatile float* vlg = lng;
    const volatile float* vlb = lnb;
    const float b1c  = vb1[col1];
    const float b2t  = vb2[tid & 127];   // used by threads < 128 in combine
    const float b3d  = vb3[d];
    const float lngd = vlg[d], lnbd = vlb[d];

    float* ztraj = out + OFF_ZT + b * 3200;   // [200][16]
    float* zdiff = out + OFF_ZD + b * 3184;   // [199][16]

    float z = ztraj[d];                       // z0, replicated, all waves

    // one evaluation of f(za); za = zarg[d] per lane (replicated x4).
    auto feval = [&](float za) -> float {
        // L1: this wave's 32 a1 columns only. zarg via readlane -> SGPR.
        float ae = 0.0f, ao = 0.0f;
#pragma unroll
        for (int k = 0; k < 16; k += 2) {
            float zk0 = readlane_f(za, k);
            float zk1 = readlane_f(za, k + 1);
            ae = fmaf(zk0, w1r[k],     ae);
            ao = fmaf(zk1, w1r[k + 1], ao);
        }
        if (lane < 32) a1s[wv][lane] = silu_f(ae + ao + b1c);
        // intra-wave write->read: compiler inserts lgkmcnt, no barrier

        // L2 partial: K-range [32wv,32wv+32), 2 cols/lane.
        // a1 via 8 broadcast b128 reads; weights pure registers.
        v2f A  = {0.0f, 0.0f}, Ab = {0.0f, 0.0f};
        v2f B  = {0.0f, 0.0f}, Bb = {0.0f, 0.0f};
        const float4* a14 = (const float4*)a1s[wv];
#pragma unroll
        for (int i = 0; i < 8; ++i) {
            float4 av = a14[i];
            v2f plo = { av.x, av.y };
            v2f phi = { av.z, av.w };
            A  = fma2(plo, w2r0[2 * i],     A);
            Ab = fma2(phi, w2r0[2 * i + 1], Ab);
            B  = fma2(plo, w2r1[2 * i],     B);
            Bb = fma2(phi, w2r1[2 * i + 1], Bb);
        }
        part[wv * 128 + c0] = A.x + A.y + Ab.x + Ab.y;
        part[wv * 128 + c1] = B.x + B.y + Bb.x + Bb.y;
        __syncthreads();                     // barrier 1

        // combine partials + bias + silu (threads 0..127, wave-uniform)
        if (tid < 128) {
            float s = part[tid] + part[128 + tid]
                    + part[256 + tid] + part[384 + tid] + b2t;
            a2s[tid] = silu_f(s);
        }
        __syncthreads();                     // barrier 2

        // L3 (replicated in all waves): output d, K-chunk g (32 wide),
        // bank-staggered broadcast b128 reads.
        v2f pp = {0.0f, 0.0f};
#pragma unroll
        for (int qq = 0; qq < 8; ++qq) {
            int qsel = (qq + 2 * g) & 7;
            float4 av = *(const float4*)&a2s[32 * g + 4 * qsel];
            pp = fma2((v2f){ av.x, av.y }, w3r[2 * qq],     pp);
            pp = fma2((v2f){ av.z, av.w }, w3r[2 * qq + 1], pp);
        }
        // cross-group combine via wave-private LDS (one round trip)
        p3s[wv * 64 + lane] = pp.x + pp.y;
        const int pb = wv * 64 + d;
        float dz = b3d + p3s[pb] + p3s[pb + 16] + p3s[pb + 32] + p3s[pb + 48];

        // One-pass LayerNorm: Σdz and Σdz² as independent DPP chains.
        float s1 = sum16_dpp(dz);
        float s2 = sum16_dpp(dz * dz);
        float m  = s1 * 0.0625f;
        float v  = fmaf(m, -m, s2 * 0.0625f);
        return (dz - m) * rsqrtf(v + 1e-5f) * lngd + lnbd;
    };

    for (int l = 0; l < 199; ++l) {
        const float dt = tvec[l + 1] - tvec[l];
        const float h  = dt * 0.125f;          // dt / K, K=8 (exact)
        const float zstart = z;
        for (int s = 0; s < 8; ++s) {
            float k1 = feval(z);
            float k2 = feval(z + h * (k1 * (float)(1.0 / 5.0)));
            float k3 = feval(z + h * ((float)(3.0 / 40.0) * k1 + (float)(9.0 / 40.0) * k2));
            float k4 = feval(z + h * ((float)(44.0 / 45.0) * k1 - (float)(56.0 / 15.0) * k2
                                    + (float)(32.0 / 9.0) * k3));
            float k5 = feval(z + h * ((float)(19372.0 / 6561.0) * k1 - (float)(25360.0 / 2187.0) * k2
                                    + (float)(64448.0 / 6561.0) * k3 - (float)(212.0 / 729.0) * k4));
            float k6 = feval(z + h * ((float)(9017.0 / 3168.0) * k1 - (float)(355.0 / 33.0) * k2
                                    + (float)(46732.0 / 5247.0) * k3 + (float)(49.0 / 176.0) * k4
                                    - (float)(5103.0 / 18656.0) * k5));
            z = z + h * ((float)(35.0 / 384.0) * k1 + (float)(500.0 / 1113.0) * k3
                       + (float)(125.0 / 192.0) * k4 - (float)(2187.0 / 6784.0) * k5
                       + (float)(11.0 / 84.0) * k6);
        }
        if (tid < 16) {
            ztraj[(l + 1) * 16 + tid] = z;
            zdiff[l * 16 + tid] = (z - zstart) / dt;
        }
    }
}

// ---------------------------------------------------------------------------
// Decoder v2: M-tile 32 rows (was 16) — halves per-row w2/w3 L2 traffic
// (4.8 GB -> 2.4 GB total). 256 threads, micro-tile 4 rows x 16 cols.
// LDS ~68 KB -> 2 blocks/CU; grid 1600.
// ---------------------------------------------------------------------------
#define GS 516   // padded LDS stride for the 32x512 activation tile

__global__ __launch_bounds__(256, 2) void dec_kernel(
    const float* __restrict__ ztr,
    const float* __restrict__ w1, const float* __restrict__ b1,
    const float* __restrict__ w2, const float* __restrict__ b2,
    const float* __restrict__ w3, const float* __restrict__ b3,
    float* __restrict__ xhat)
{
    __shared__ __align__(16) float zt[32 * 17];
    __shared__ __align__(16) float g[32 * GS];

    const int t    = threadIdx.x;
    const int blk  = blockIdx.x;
    const int tr   = t >> 5;         // 0..7
    const int tc   = t & 31;         // 0..31
    const int row0 = blk * 32;
    const int r0   = 4 * tr;         // 4-row micro-tile

    {
        int i0 = t, i1 = t + 256;
        zt[(i0 >> 4) * 17 + (i0 & 15)] = ztr[(row0 + (i0 >> 4)) * 16 + (i0 & 15)];
        zt[(i1 >> 4) * 17 + (i1 & 15)] = ztr[(row0 + (i1 >> 4)) * 16 + (i1 & 15)];
    }
    __syncthreads();

    // Phase A: g1 = relu(z @ w1 + b1), K=16, 4 rows/thread
    {
        float acc[4][16];
#pragma unroll
        for (int p = 0; p < 4; ++p)
#pragma unroll
            for (int i = 0; i < 16; ++i) acc[p][i] = 0.0f;

#pragma unroll
        for (int k = 0; k < 16; ++k) {
            float a0 = zt[(r0 + 0) * 17 + k];
            float a1 = zt[(r0 + 1) * 17 + k];
            float a2 = zt[(r0 + 2) * 17 + k];
            float a3 = zt[(r0 + 3) * 17 + k];
            const float4* wr = (const float4*)(w1 + k * 512 + 16 * tc);
#pragma unroll
            for (int u = 0; u < 4; ++u) {
                float4 wv = wr[u];
                acc[0][4 * u + 0] = fmaf(a0, wv.x, acc[0][4 * u + 0]);
                acc[0][4 * u + 1] = fmaf(a0, wv.y, acc[0][4 * u + 1]);
                acc[0][4 * u + 2] = fmaf(a0, wv.z, acc[0][4 * u + 2]);
                acc[0][4 * u + 3] = fmaf(a0, wv.w, acc[0][4 * u + 3]);
                acc[1][4 * u + 0] = fmaf(a1, wv.x, acc[1][4 * u + 0]);
                acc[1][4 * u + 1] = fmaf(a1, wv.y, acc[1][4 * u + 1]);
                acc[1][4 * u + 2] = fmaf(a1, wv.z, acc[1][4 * u + 2]);
                acc[1][4 * u + 3] = fmaf(a1, wv.w, acc[1][4 * u + 3]);
                acc[2][4 * u + 0] = fmaf(a2, wv.x, acc[2][4 * u + 0]);
                acc[2][4 * u + 1] = fmaf(a2, wv.y, acc[2][4 * u + 1]);
                acc[2][4 * u + 2] = fmaf(a2, wv.z, acc[2][4 * u + 2]);
                acc[2][4 * u + 3] = fmaf(a2, wv.w, acc[2][4 * u + 3]);
                acc[3][4 * u + 0] = fmaf(a3, wv.x, acc[3][4 * u + 0]);
                acc[3][4 * u + 1] = fmaf(a3, wv.y, acc[3][4 * u + 1]);
                acc[3][4 * u + 2] = fmaf(a3, wv.z, acc[3][4 * u + 2]);
                acc[3][4 * u + 3] = fmaf(a3, wv.w, acc[3][4 * u + 3]);
            }
        }
        const float4* bb = (const float4*)(b1 + 16 * tc);
#pragma unroll
        for (int u = 0; u < 4; ++u) {
            float4 bv = bb[u];
#pragma unroll
            for (int p = 0; p < 4; ++p) {
                g[(r0 + p) * GS + 16 * tc + 4 * u + 0] = fmaxf(acc[p][4 * u + 0] + bv.x, 0.0f);
                g[(r0 + p) * GS + 16 * tc + 4 * u + 1] = fmaxf(acc[p][4 * u + 1] + bv.y, 0.0f);
                g[(r0 + p) * GS + 16 * tc + 4 * u + 2] = fmaxf(acc[p][4 * u + 2] + bv.z, 0.0f);
                g[(r0 + p) * GS + 16 * tc + 4 * u + 3] = fmaxf(acc[p][4 * u + 3] + bv.w, 0.0f);
            }
        }
    }
    __syncthreads();

    // Phase B: g2 = relu(g1 @ w2 + b2), K=512, 4 rows/thread
    {
        float accB[4][16];
#pragma unroll
        for (int p = 0; p < 4; ++p)
#pragma unroll
            for (int i = 0; i < 16; ++i) accB[p][i] = 0.0f;

        for (int k4 = 0; k4 < 128; ++k4) {
            float4 av0 = *(const float4*)&g[(r0 + 0) * GS + 4 * k4];
            float4 av1 = *(const float4*)&g[(r0 + 1) * GS + 4 * k4];
            float4 av2 = *(const float4*)&g[(r0 + 2) * GS + 4 * k4];
            float4 av3 = *(const float4*)&g[(r0 + 3) * GS + 4 * k4];
            float a0[4] = {av0.x, av0.y, av0.z, av0.w};
            float a1[4] = {av1.x, av1.y, av1.z, av1.w};
            float a2[4] = {av2.x, av2.y, av2.z, av2.w};
            float a3[4] = {av3.x, av3.y, av3.z, av3.w};
#pragma unroll
            for (int u = 0; u < 4; ++u) {
                const float4* wr = (const float4*)(w2 + (4 * k4 + u) * 512 + 16 * tc);
#pragma unroll
                for (int q = 0; q < 4; ++q) {
                    float4 wv = wr[q];
                    accB[0][4 * q + 0] = fmaf(a0[u], wv.x, accB[0][4 * q + 0]);
                    accB[0][4 * q + 1] = fmaf(a0[u], wv.y, accB[0][4 * q + 1]);
                    accB[0][4 * q + 2] = fmaf(a0[u], wv.z, accB[0][4 * q + 2]);
                    accB[0][4 * q + 3] = fmaf(a0[u], wv.w, accB[0][4 * q + 3]);
                    accB[1][4 * q + 0] = fmaf(a1[u], wv.x, accB[1][4 * q + 0]);
                    accB[1][4 * q + 1] = fmaf(a1[u], wv.y, accB[1][4 * q + 1]);
                    accB[1][4 * q + 2] = fmaf(a1[u], wv.z, accB[1][4 * q + 2]);
                    accB[1][4 * q + 3] = fmaf(a1[u], wv.w, accB[1][4 * q + 3]);
                    accB[2][4 * q + 0] = fmaf(a2[u], wv.x, accB[2][4 * q + 0]);
                    accB[2][4 * q + 1] = fmaf(a2[u], wv.y, accB[2][4 * q + 1]);
                    accB[2][4 * q + 2] = fmaf(a2[u], wv.z, accB[2][4 * q + 2]);
                    accB[2][4 * q + 3] = fmaf(a2[u], wv.w, accB[2][4 * q + 3]);
                    accB[3][4 * q + 0] = fmaf(a3[u], wv.x, accB[3][4 * q + 0]);
                    accB[3][4 * q + 1] = fmaf(a3[u], wv.y, accB[3][4 * q + 1]);
                    accB[3][4 * q + 2] = fmaf(a3[u], wv.z, accB[3][4 * q + 2]);
                    accB[3][4 * q + 3] = fmaf(a3[u], wv.w, accB[3][4 * q + 3]);
                }
            }
        }
        __syncthreads();   // everyone done reading g1
        const float4* bb = (const float4*)(b2 + 16 * tc);
#pragma unroll
        for (int u = 0; u < 4; ++u) {
            float4 bv = bb[u];
#pragma unroll
            for (int p = 0; p < 4; ++p) {
                g[(r0 + p) * GS + 16 * tc + 4 * u + 0] = fmaxf(accB[p][4 * u + 0] + bv.x, 0.0f);
                g[(r0 + p) * GS + 16 * tc + 4 * u + 1] = fmaxf(accB[p][4 * u + 1] + bv.y, 0.0f);
                g[(r0 + p) * GS + 16 * tc + 4 * u + 2] = fmaxf(accB[p][4 * u + 2] + bv.z, 0.0f);
                g[(r0 + p) * GS + 16 * tc + 4 * u + 3] = fmaxf(accB[p][4 * u + 3] + bv.w, 0.0f);
            }
        }
    }
    __syncthreads();

    // Phase C: xhat = g2 @ w3 + b3, N=256 (8 cols/thread), K=512, 4 rows
    {
        float accC[4][8];
#pragma unroll
        for (int p = 0; p < 4; ++p)
#pragma unroll
            for (int i = 0; i < 8; ++i) accC[p][i] = 0.0f;

        for (int k4 = 0; k4 < 128; ++k4) {
            float4 av0 = *(const float4*)&g[(r0 + 0) * GS + 4 * k4];
            float4 av1 = *(const float4*)&g[(r0 + 1) * GS + 4 * k4];
            float4 av2 = *(const float4*)&g[(r0 + 2) * GS + 4 * k4];
            float4 av3 = *(const float4*)&g[(r0 + 3) * GS + 4 * k4];
            float a0[4] = {av0.x, av0.y, av0.z, av0.w};
            float a1[4] = {av1.x, av1.y, av1.z, av1.w};
            float a2[4] = {av2.x, av2.y, av2.z, av2.w};
            float a3[4] = {av3.x, av3.y, av3.z, av3.w};
#pragma unroll
            for (int u = 0; u < 4; ++u) {
                const float4* wr = (const float4*)(w3 + (4 * k4 + u) * 256 + 8 * tc);
                float4 w0 = wr[0], w1v = wr[1];
                accC[0][0] = fmaf(a0[u], w0.x,  accC[0][0]);
                accC[0][1] = fmaf(a0[u], w0.y,  accC[0][1]);
                accC[0][2] = fmaf(a0[u], w0.z,  accC[0][2]);
                accC[0][3] = fmaf(a0[u], w0.w,  accC[0][3]);
                accC[0][4] = fmaf(a0[u], w1v.x, accC[0][4]);
                accC[0][5] = fmaf(a0[u], w1v.y, accC[0][5]);
                accC[0][6] = fmaf(a0[u], w1v.z, accC[0][6]);
                accC[0][7] = fmaf(a0[u], w1v.w, accC[0][7]);
                accC[1][0] = fmaf(a1[u], w0.x,  accC[1][0]);
                accC[1][1] = fmaf(a1[u], w0.y,  accC[1][1]);
                accC[1][2] = fmaf(a1[u], w0.z,  accC[1][2]);
                accC[1][3] = fmaf(a1[u], w0.w,  accC[1][3]);
                accC[1][4] = fmaf(a1[u], w1v.x, accC[1][4]);
                accC[1][5] = fmaf(a1[u], w1v.y, accC[1][5]);
                accC[1][6] = fmaf(a1[u], w1v.z, accC[1][6]);
                accC[1][7] = fmaf(a1[u], w1v.w, accC[1][7]);
                accC[2][0] = fmaf(a2[u], w0.x,  accC[2][0]);
                accC[2][1] = fmaf(a2[u], w0.y,  accC[2][1]);
                accC[2][2] = fmaf(a2[u], w0.z,  accC[2][2]);
                accC[2][3] = fmaf(a2[u], w0.w,  accC[2][3]);
                accC[2][4] = fmaf(a2[u], w1v.x, accC[2][4]);
                accC[2][5] = fmaf(a2[u], w1v.y, accC[2][5]);
                accC[2][6] = fmaf(a2[u], w1v.z, accC[2][6]);
                accC[2][7] = fmaf(a2[u], w1v.w, accC[2][7]);
                accC[3][0] = fmaf(a3[u], w0.x,  accC[3][0]);
                accC[3][1] = fmaf(a3[u], w0.y,  accC[3][1]);
                accC[3][2] = fmaf(a3[u], w0.z,  accC[3][2]);
                accC[3][3] = fmaf(a3[u], w0.w,  accC[3][3]);
                accC[3][4] = fmaf(a3[u], w1v.x, accC[3][4]);
                accC[3][5] = fmaf(a3[u], w1v.y, accC[3][5]);
                accC[3][6] = fmaf(a3[u], w1v.z, accC[3][6]);
                accC[3][7] = fmaf(a3[u], w1v.w, accC[3][7]);
            }
        }
        const float4* bb = (const float4*)(b3 + 8 * tc);
        float4 bv0 = bb[0], bv1 = bb[1];
#pragma unroll
        for (int p = 0; p < 4; ++p) {
            float4 o0 = make_float4(accC[p][0] + bv0.x, accC[p][1] + bv0.y,
                                    accC[p][2] + bv0.z, accC[p][3] + bv0.w);
            float4 o1 = make_float4(accC[p][4] + bv1.x, accC[p][5] + bv1.y,
                                    accC[p][6] + bv1.z, accC[p][7] + bv1.w);
            float* dst = xhat + (size_t)(row0 + r0 + p) * 256 + 8 * tc;
            *(float4*)(dst)     = o0;
            *(float4*)(dst + 4) = o1;
        }
    }
}

extern "C" void kernel_launch(void* const* d_in, const int* in_sizes, int n_in,
                              void* d_out, int out_size, void* d_ws, size_t ws_size,
                              hipStream_t stream) {
    const float* x_seq  = (const float*)d_in[0];
    const float* tvec   = (const float*)d_in[1];
    const float* eps    = (const float*)d_in[2];
    const float* enc_w1 = (const float*)d_in[3];
    const float* enc_b1 = (const float*)d_in[4];
    const float* enc_w2 = (const float*)d_in[5];
    const float* enc_b2 = (const float*)d_in[6];
    const float* enc_w3 = (const float*)d_in[7];
    const float* enc_b3 = (const float*)d_in[8];
    const float* mu_w   = (const float*)d_in[9];
    const float* mu_b   = (const float*)d_in[10];
    const float* lv_w   = (const float*)d_in[11];
    const float* lv_b   = (const float*)d_in[12];
    const float* ode_w1 = (const float*)d_in[13];
    const float* ode_b1 = (const float*)d_in[14];
    const float* ode_w2 = (const float*)d_in[15];
    const float* ode_b2 = (const float*)d_in[16];
    const float* ode_w3 = (const float*)d_in[17];
    const float* ode_b3 = (const float*)d_in[18];
    const float* ln_g   = (const float*)d_in[19];
    const float* ln_b   = (const float*)d_in[20];
    const float* dec_w1 = (const float*)d_in[21];
    const float* dec_b1 = (const float*)d_in[22];
    const float* dec_w2 = (const float*)d_in[23];
    const float* dec_b2 = (const float*)d_in[24];
    const float* dec_w3 = (const float*)d_in[25];
    const float* dec_b3 = (const float*)d_in[26];
    float* out = (float*)d_out;

    enc_kernel<<<256, 256, 0, stream>>>(x_seq, eps, enc_w1, enc_b1, enc_w2, enc_b2,
                                        enc_w3, enc_b3, mu_w, mu_b, lv_w, lv_b, out);
    ode_kernel<<<256, 256, 0, stream>>>(tvec, ode_w1, ode_b1, ode_w2, ode_b2,
                                        ode_w3, ode_b3, ln_g, ln_b, out);
    dec_kernel<<<1600, 256, 0, stream>>>(out + OFF_ZT, dec_w1, dec_b1, dec_w2, dec_b2,
                                         dec_w3, dec_b3, out);
}